// Round 2
// baseline (509.799 us; speedup 1.0000x reference)
//
#include <hip/hip_runtime.h>
#include <hip/hip_bf16.h>

// Problem dims (fixed)
#define T_DIM 256
#define B_DIM 256
#define F_DIM 128
#define H1_DIM 256
#define H_DIM 128
#define Q_DIM 4
#define TAGS 32
#define TB (T_DIM * B_DIM)   // 65536 rows

__device__ __forceinline__ float tanhf_fast(float x) {
    // 1 - 2/(exp(2x)+1): safe at +/-inf
    float e = __expf(2.0f * x);
    return 1.0f - 2.0f / (e + 1.0f);
}
__device__ __forceinline__ float sigf(float x) {
    return 1.0f / (1.0f + __expf(-x));
}

// ---------------------------------------------------------------------------
// Kernel 1: per-node MLP. node_states = tanh(tanh(X@W1+b1)@W2+b2)
// Block: 256 threads, 32 rows per block. Grid: TB/32 = 2048.
// ---------------------------------------------------------------------------
__global__ __launch_bounds__(256) void mlp_kernel(
    const float* __restrict__ X, const float* __restrict__ W1,
    const float* __restrict__ b1, const float* __restrict__ W2,
    const float* __restrict__ b2, float* __restrict__ NS)
{
    __shared__ float xs[32 * 128];    // 16 KB
    __shared__ float a1s[32 * 256];   // 32 KB
    const int tid = threadIdx.x;
    const long rowbase = (long)blockIdx.x * 32;

    // stage X tile (32 x 128)
    {
        const float4* Xg = (const float4*)(X + rowbase * 128);
        float4* xs4 = (float4*)xs;
#pragma unroll
        for (int i = 0; i < 4; i++) xs4[tid + i * 256] = Xg[tid + i * 256];
    }
    __syncthreads();

    // Phase A: a1 = tanh(x @ W1 + b1)   [32 x 256]
    {
        const int rg = tid >> 6;        // 0..3 -> rows rg*8..rg*8+7
        const int c0 = tid & 63;        // cols c0 + 64*j, j<4
        float acc[8][4];
#pragma unroll
        for (int r = 0; r < 8; r++)
#pragma unroll
            for (int j = 0; j < 4; j++) acc[r][j] = 0.0f;

        const float4* xs4 = (const float4*)xs;
        for (int k4 = 0; k4 < 32; k4++) {
            float4 xv[8];
#pragma unroll
            for (int r = 0; r < 8; r++) xv[r] = xs4[(rg * 8 + r) * 32 + k4];
            float wv[4][4];
#pragma unroll
            for (int kk = 0; kk < 4; kk++)
#pragma unroll
                for (int j = 0; j < 4; j++)
                    wv[kk][j] = W1[(k4 * 4 + kk) * 256 + c0 + 64 * j];
#pragma unroll
            for (int r = 0; r < 8; r++) {
#pragma unroll
                for (int j = 0; j < 4; j++) {
                    acc[r][j] += xv[r].x * wv[0][j] + xv[r].y * wv[1][j]
                               + xv[r].z * wv[2][j] + xv[r].w * wv[3][j];
                }
            }
        }
#pragma unroll
        for (int r = 0; r < 8; r++)
#pragma unroll
            for (int j = 0; j < 4; j++) {
                int c = c0 + 64 * j;
                a1s[(rg * 8 + r) * 256 + c] = tanhf_fast(acc[r][j] + b1[c]);
            }
    }
    __syncthreads();

    // Phase B: ns = tanh(a1 @ W2 + b2)   [32 x 128]
    {
        const int rg = tid >> 6;        // 0..3 -> rows rg*8..rg*8+7
        const int c0 = tid & 63;        // cols c0 + 64*j, j<2
        float acc[8][2];
#pragma unroll
        for (int r = 0; r < 8; r++)
#pragma unroll
            for (int j = 0; j < 2; j++) acc[r][j] = 0.0f;

        const float4* a1s4 = (const float4*)a1s;
        for (int k4 = 0; k4 < 64; k4++) {
            float4 av[8];
#pragma unroll
            for (int r = 0; r < 8; r++) av[r] = a1s4[(rg * 8 + r) * 64 + k4];
            float wv[4][2];
#pragma unroll
            for (int kk = 0; kk < 4; kk++)
#pragma unroll
                for (int j = 0; j < 2; j++)
                    wv[kk][j] = W2[(k4 * 4 + kk) * 128 + c0 + 64 * j];
#pragma unroll
            for (int r = 0; r < 8; r++) {
#pragma unroll
                for (int j = 0; j < 2; j++) {
                    acc[r][j] += av[r].x * wv[0][j] + av[r].y * wv[1][j]
                               + av[r].z * wv[2][j] + av[r].w * wv[3][j];
                }
            }
        }
#pragma unroll
        for (int r = 0; r < 8; r++)
#pragma unroll
            for (int j = 0; j < 2; j++) {
                int c = c0 + 64 * j;
                long row = rowbase + rg * 8 + r;
                NS[row * 128 + c] = tanhf_fast(acc[r][j] + b2[c]);
            }
    }
}

// ---------------------------------------------------------------------------
// Kernel 2: aggregation. AG[t,i,f] = sum_j adj[i,j] * NS[t,j,f]
// Grid: (8 i-tiles, 256 t). Block 256. Each block: 32 i x 128 f.
// ---------------------------------------------------------------------------
__global__ __launch_bounds__(256) void agg_kernel(
    const float* __restrict__ adj, const float* __restrict__ NS,
    float* __restrict__ AG)
{
    __shared__ float nst[32 * 128];   // 16 KB
    __shared__ float adjT[32 * 32];   // 4 KB, [j][i]
    const int tid = threadIdx.x;
    const int t = blockIdx.y;
    const int i0 = blockIdx.x * 32;
    const long nsbase = (long)t * (B_DIM * H_DIM);

    const int ig = tid >> 5;   // 0..7 -> i = i0 + ig*4 + r
    const int f4 = tid & 31;   // f = f4*4 .. +3

    float4 acc[4];
#pragma unroll
    for (int r = 0; r < 4; r++) acc[r] = make_float4(0.f, 0.f, 0.f, 0.f);

    for (int j0 = 0; j0 < 256; j0 += 32) {
        __syncthreads();
        // stage NS rows j0..j0+31 (32x128)
        {
            const float4* g = (const float4*)(NS + nsbase + (long)j0 * 128);
            float4* s4 = (float4*)nst;
#pragma unroll
            for (int i = 0; i < 4; i++) s4[tid + i * 256] = g[tid + i * 256];
        }
        // stage adj tile transposed
        {
            int ii = tid >> 3;
            int jj4 = (tid & 7) * 4;
            float4 a = *(const float4*)(adj + (long)(i0 + ii) * 256 + j0 + jj4);
            adjT[(jj4 + 0) * 32 + ii] = a.x;
            adjT[(jj4 + 1) * 32 + ii] = a.y;
            adjT[(jj4 + 2) * 32 + ii] = a.z;
            adjT[(jj4 + 3) * 32 + ii] = a.w;
        }
        __syncthreads();

        const float4* adjT4 = (const float4*)adjT;
        const float4* nst4 = (const float4*)nst;
#pragma unroll 8
        for (int jj = 0; jj < 32; jj++) {
            float4 av = adjT4[jj * 8 + ig];
            float4 nv = nst4[jj * 32 + f4];
            acc[0].x += av.x * nv.x; acc[0].y += av.x * nv.y; acc[0].z += av.x * nv.z; acc[0].w += av.x * nv.w;
            acc[1].x += av.y * nv.x; acc[1].y += av.y * nv.y; acc[1].z += av.y * nv.z; acc[1].w += av.y * nv.w;
            acc[2].x += av.z * nv.x; acc[2].y += av.z * nv.y; acc[2].z += av.z * nv.z; acc[2].w += av.z * nv.w;
            acc[3].x += av.w * nv.x; acc[3].y += av.w * nv.y; acc[3].z += av.w * nv.z; acc[3].w += av.w * nv.w;
        }
    }
#pragma unroll
    for (int r = 0; r < 4; r++) {
        long base = (long)t * (B_DIM * H_DIM) + (long)(i0 + ig * 4 + r) * 128;
        *(float4*)(AG + base + f4 * 4) = acc[r];
    }
}

// ---------------------------------------------------------------------------
// Kernel 3: Ax[t,b,o] = AG[t,b,:] @ Win[g, 0:128, q] + b_in[o]   (o = g*4+q)
// ---------------------------------------------------------------------------
__global__ __launch_bounds__(256) void ax_kernel(
    const float* __restrict__ AG, const float* __restrict__ Win,
    const float* __restrict__ b_in, float* __restrict__ AX)
{
    long gid = (long)blockIdx.x * 256 + threadIdx.x;  // < TB*16
    long row = gid >> 4;
    int o = (int)(gid & 15);
    int g = o >> 2, q = o & 3;
    const float4* xr = (const float4*)(AG + row * 128);
    const float* wb = Win + g * 1024 + q;   // Win[g][k][q], stride 4 over k
    float acc = b_in[o];
#pragma unroll 8
    for (int k4 = 0; k4 < 32; k4++) {
        float4 xv = xr[k4];
        acc += xv.x * wb[(k4 * 4 + 0) * 4] + xv.y * wb[(k4 * 4 + 1) * 4]
             + xv.z * wb[(k4 * 4 + 2) * 4] + xv.w * wb[(k4 * 4 + 3) * 4];
    }
    AX[gid] = acc;
}

// ---------------------------------------------------------------------------
// Kernel 4: LSTM scan. One block (64 threads = 1 wave) per batch element b.
// Per step: zpre = Ax[t,b,:] + h @ Win_h ; z=tanh ; g = z@Wout + b_out ;
// gates -> c,h update ; write h to HS[t,b,:].
// ---------------------------------------------------------------------------
__global__ __launch_bounds__(64) void lstm_kernel(
    const float* __restrict__ AX, const float* __restrict__ Win,
    const float* __restrict__ Wout, const float* __restrict__ b_out,
    float* __restrict__ HS)
{
    __shared__ __align__(16) float h_lds[128];
    __shared__ __align__(16) float z_lds[16];

    const int lane = threadIdx.x;
    const int b = blockIdx.x;
    const int o = lane >> 2;      // 0..15 : which (g,q) output this group computes
    const int s = lane & 3;       // k-split 0..3
    const int g_o = o >> 2, q_o = o & 3;

    // preload Win_h slice: Win[g][128+k][q] for k = s*32 .. s*32+31
    float wh[32];
#pragma unroll
    for (int m = 0; m < 32; m++) {
        int k = s * 32 + m;
        wh[m] = Win[g_o * 1024 + 512 + k * 4 + q_o];
    }
    // preload Wout / b_out for my two h-features j = lane, lane+64
    float wo[4][4][2];
    float bo[4][2];
#pragma unroll
    for (int g = 0; g < 4; g++) {
#pragma unroll
        for (int h2 = 0; h2 < 2; h2++) bo[g][h2] = b_out[g * 128 + lane + 64 * h2];
#pragma unroll
        for (int q = 0; q < 4; q++)
#pragma unroll
            for (int h2 = 0; h2 < 2; h2++)
                wo[g][q][h2] = Wout[(g * 4 + q) * 128 + lane + 64 * h2];
    }

    float c[2] = {0.f, 0.f};
    h_lds[lane] = 0.f;
    h_lds[lane + 64] = 0.f;
    __syncthreads();

    float ax_cur = AX[(long)b * 16 + o];

    for (int t = 0; t < T_DIM; t++) {
        // zpre partial: sum over k = s*32 .. s*32+31 of h[k]*Win_h[k][o]
        float acc = 0.f;
        const float4* h4 = (const float4*)h_lds;
#pragma unroll
        for (int m = 0; m < 8; m++) {
            float4 hv = h4[s * 8 + m];
            acc += hv.x * wh[m * 4 + 0] + hv.y * wh[m * 4 + 1]
                 + hv.z * wh[m * 4 + 2] + hv.w * wh[m * 4 + 3];
        }
        acc += __shfl_xor(acc, 1);
        acc += __shfl_xor(acc, 2);
        float zv = tanhf_fast(acc + ax_cur);

        // prefetch next timestep's Ax while we crunch
        if (t + 1 < T_DIM) ax_cur = AX[(long)(t + 1) * (B_DIM * 16) + (long)b * 16 + o];

        if (s == 0) z_lds[o] = zv;
        __syncthreads();

        const float4* z4 = (const float4*)z_lds;
        float4 zg0 = z4[0], zg1 = z4[1], zg2 = z4[2], zg3 = z4[3];

        float hv_out[2];
#pragma unroll
        for (int h2 = 0; h2 < 2; h2++) {
            float gp_f = bo[0][h2] + zg0.x * wo[0][0][h2] + zg0.y * wo[0][1][h2]
                                   + zg0.z * wo[0][2][h2] + zg0.w * wo[0][3][h2];
            float gp_i = bo[1][h2] + zg1.x * wo[1][0][h2] + zg1.y * wo[1][1][h2]
                                   + zg1.z * wo[1][2][h2] + zg1.w * wo[1][3][h2];
            float gp_g = bo[2][h2] + zg2.x * wo[2][0][h2] + zg2.y * wo[2][1][h2]
                                   + zg2.z * wo[2][2][h2] + zg2.w * wo[2][3][h2];
            float gp_o = bo[3][h2] + zg3.x * wo[3][0][h2] + zg3.y * wo[3][1][h2]
                                   + zg3.z * wo[3][2][h2] + zg3.w * wo[3][3][h2];
            float fg = sigf(gp_f);
            float ig = sigf(gp_i);
            float gg = tanhf_fast(gp_g);
            float og = sigf(gp_o);
            c[h2] = fg * c[h2] + ig * gg;
            hv_out[h2] = og * tanhf_fast(c[h2]);
        }
        __syncthreads();
        h_lds[lane] = hv_out[0];
        h_lds[lane + 64] = hv_out[1];
        long outbase = (long)t * (B_DIM * H_DIM) + (long)b * H_DIM;
        HS[outbase + lane] = hv_out[0];
        HS[outbase + lane + 64] = hv_out[1];
        __syncthreads();
    }
}

// ---------------------------------------------------------------------------
// Kernel 5: tag head + log_softmax. OUT[row, tag] over 32 tags.
// Block 256 = 8 rows x 32 tags. Grid TB/8 = 8192.
// ---------------------------------------------------------------------------
__global__ __launch_bounds__(256) void head_kernel(
    const float* __restrict__ HS, const float* __restrict__ Wtag,
    const float* __restrict__ btag, float* __restrict__ OUT)
{
    __shared__ float wt[128 * 32];   // 16 KB
    const int tid = threadIdx.x;
    {
        float4* wt4 = (float4*)wt;
        const float4* wg = (const float4*)Wtag;
#pragma unroll
        for (int i = 0; i < 4; i++) wt4[tid + i * 256] = wg[tid + i * 256];
    }
    __syncthreads();

    long row = (long)blockIdx.x * 8 + (tid >> 5);
    int tag = tid & 31;
    const float4* xr = (const float4*)(HS + row * 128);
    float acc = btag[tag];
#pragma unroll 8
    for (int k4 = 0; k4 < 32; k4++) {
        float4 xv = xr[k4];
        acc += xv.x * wt[(k4 * 4 + 0) * 32 + tag] + xv.y * wt[(k4 * 4 + 1) * 32 + tag]
             + xv.z * wt[(k4 * 4 + 2) * 32 + tag] + xv.w * wt[(k4 * 4 + 3) * 32 + tag];
    }
    float m = acc;
#pragma unroll
    for (int d = 16; d >= 1; d >>= 1) m = fmaxf(m, __shfl_xor(m, d));
    float e = __expf(acc - m);
#pragma unroll
    for (int d = 16; d >= 1; d >>= 1) e += __shfl_xor(e, d);
    OUT[row * 32 + tag] = acc - m - __logf(e);
}

// ---------------------------------------------------------------------------
extern "C" void kernel_launch(void* const* d_in, const int* in_sizes, int n_in,
                              void* d_out, int out_size, void* d_ws, size_t ws_size,
                              hipStream_t stream)
{
    const float* X    = (const float*)d_in[0];   // [T,B,F]
    const float* adj  = (const float*)d_in[1];   // [B,B]
    const float* W1   = (const float*)d_in[2];   // [F,H1]
    const float* b1   = (const float*)d_in[3];
    const float* W2   = (const float*)d_in[4];   // [H1,H]
    const float* b2   = (const float*)d_in[5];
    const float* Win  = (const float*)d_in[6];   // [4,F+H,Q]
    const float* b_in = (const float*)d_in[7];   // [4,Q]
    const float* Wout = (const float*)d_in[8];   // [4,Q,H]
    const float* bout = (const float*)d_in[9];   // [4,H]
    const float* Wtag = (const float*)d_in[10];  // [H,TAGS]
    const float* btag = (const float*)d_in[11];
    float* OUT = (float*)d_out;

    float* ws = (float*)d_ws;
    float* NS = ws;                       // [T,B,H]  8,388,608 f
    float* AG = ws + 8388608;             // [T,B,H]  8,388,608 f
    float* AX = ws + 16777216;            // [T,B,16] 1,048,576 f
    float* HS = NS;                       // lstm_out reuses NS region

    mlp_kernel<<<dim3(TB / 32), dim3(256), 0, stream>>>(X, W1, b1, W2, b2, NS);
    agg_kernel<<<dim3(8, 256), dim3(256), 0, stream>>>(adj, NS, AG);
    ax_kernel<<<dim3(TB * 16 / 256), dim3(256), 0, stream>>>(AG, Win, b_in, AX);
    lstm_kernel<<<dim3(B_DIM), dim3(64), 0, stream>>>(AX, Win, Wout, bout, HS);
    head_kernel<<<dim3(TB / 8), dim3(256), 0, stream>>>(HS, Wtag, btag, OUT);
}

// Round 3
// 383.486 us; speedup vs baseline: 1.3294x; 1.3294x over previous
//
#include <hip/hip_runtime.h>
#include <hip/hip_bf16.h>

// Problem dims (fixed)
#define T_DIM 256
#define B_DIM 256
#define F_DIM 128
#define H1_DIM 256
#define H_DIM 128
#define Q_DIM 4
#define TAGS 32
#define TB (T_DIM * B_DIM)   // 65536 rows

__device__ __forceinline__ float tanhf_fast(float x) {
    float e = __expf(2.0f * x);
    return 1.0f - 2.0f / (e + 1.0f);
}
__device__ __forceinline__ float sigf(float x) {
    return 1.0f / (1.0f + __expf(-x));
}

// ---------------------------------------------------------------------------
// Kernel 1: per-node MLP + fused Win_x projection.
// NSP[row, o] = tanh(tanh(X@W1+b1)@W2+b2) @ Win_x[:,o]     (o = g*4+q, 16 outs)
// Block: 256 threads, 32 rows per block. Grid: TB/32 = 2048.
// ---------------------------------------------------------------------------
__global__ __launch_bounds__(256) void mlp_kernel(
    const float* __restrict__ X, const float* __restrict__ W1,
    const float* __restrict__ b1, const float* __restrict__ W2,
    const float* __restrict__ b2, const float* __restrict__ Win,
    float* __restrict__ NSP)
{
    __shared__ float smemA[32 * 132];   // xs [32][128] then nss [32][132]
    __shared__ float smemB[32 * 256];   // a1s [32][256] then wxsT [16][132]
    const int tid = threadIdx.x;
    const long rowbase = (long)blockIdx.x * 32;

    // stage X tile (32 x 128) into smemA (stride 128)
    {
        const float4* Xg = (const float4*)(X + rowbase * 128);
        float4* xs4 = (float4*)smemA;
#pragma unroll
        for (int i = 0; i < 4; i++) xs4[tid + i * 256] = Xg[tid + i * 256];
    }
    __syncthreads();

    // Phase A: a1 = tanh(x @ W1 + b1)   [32 x 256] -> smemB
    {
        const int rg = tid >> 6;
        const int c0 = tid & 63;
        float acc[8][4];
#pragma unroll
        for (int r = 0; r < 8; r++)
#pragma unroll
            for (int j = 0; j < 4; j++) acc[r][j] = 0.0f;

        const float4* xs4 = (const float4*)smemA;
        for (int k4 = 0; k4 < 32; k4++) {
            float4 xv[8];
#pragma unroll
            for (int r = 0; r < 8; r++) xv[r] = xs4[(rg * 8 + r) * 32 + k4];
            float wv[4][4];
#pragma unroll
            for (int kk = 0; kk < 4; kk++)
#pragma unroll
                for (int j = 0; j < 4; j++)
                    wv[kk][j] = W1[(k4 * 4 + kk) * 256 + c0 + 64 * j];
#pragma unroll
            for (int r = 0; r < 8; r++)
#pragma unroll
                for (int j = 0; j < 4; j++)
                    acc[r][j] += xv[r].x * wv[0][j] + xv[r].y * wv[1][j]
                               + xv[r].z * wv[2][j] + xv[r].w * wv[3][j];
        }
#pragma unroll
        for (int r = 0; r < 8; r++)
#pragma unroll
            for (int j = 0; j < 4; j++) {
                int c = c0 + 64 * j;
                smemB[(rg * 8 + r) * 256 + c] = tanhf_fast(acc[r][j] + b1[c]);
            }
    }
    __syncthreads();

    // Phase B: ns = tanh(a1 @ W2 + b2)   [32 x 128] -> nss in smemA (stride 132)
    {
        const int rg = tid >> 6;
        const int c0 = tid & 63;
        float acc[8][2];
#pragma unroll
        for (int r = 0; r < 8; r++)
#pragma unroll
            for (int j = 0; j < 2; j++) acc[r][j] = 0.0f;

        const float4* a1s4 = (const float4*)smemB;
        for (int k4 = 0; k4 < 64; k4++) {
            float4 av[8];
#pragma unroll
            for (int r = 0; r < 8; r++) av[r] = a1s4[(rg * 8 + r) * 64 + k4];
            float wv[4][2];
#pragma unroll
            for (int kk = 0; kk < 4; kk++)
#pragma unroll
                for (int j = 0; j < 2; j++)
                    wv[kk][j] = W2[(k4 * 4 + kk) * 128 + c0 + 64 * j];
#pragma unroll
            for (int r = 0; r < 8; r++)
#pragma unroll
                for (int j = 0; j < 2; j++)
                    acc[r][j] += av[r].x * wv[0][j] + av[r].y * wv[1][j]
                               + av[r].z * wv[2][j] + av[r].w * wv[3][j];
        }
        // write ns into nss (smemA, stride 132) — disjoint from smemB reads
#pragma unroll
        for (int r = 0; r < 8; r++)
#pragma unroll
            for (int j = 0; j < 2; j++) {
                int c = c0 + 64 * j;
                smemA[(rg * 8 + r) * 132 + c] = tanhf_fast(acc[r][j] + b2[c]);
            }
    }
    __syncthreads();   // all Phase-B a1s reads done -> can overwrite smemB

    // stage Win_x transposed: wxsT[o][f] = Win[g][f][q], o=g*4+q  (16 x 132)
    for (int idx = tid; idx < 2048; idx += 256) {
        int o = idx >> 7, f = idx & 127;
        smemB[o * 132 + f] = Win[(o >> 2) * 1024 + f * 4 + (o & 3)];
    }
    __syncthreads();

    // NSP gemm: 32 rows x 16 o, 2 o per thread
    {
        const int row = tid >> 3;
        const int o0 = (tid & 7) * 2;
        const float4* nss4 = (const float4*)smemA;
        const float4* wx4 = (const float4*)smemB;
        float a0 = 0.f, a1 = 0.f;
#pragma unroll
        for (int f4 = 0; f4 < 32; f4++) {
            float4 nv = nss4[row * 33 + f4];
            float4 w0 = wx4[o0 * 33 + f4];
            float4 w1 = wx4[(o0 + 1) * 33 + f4];
            a0 += nv.x * w0.x + nv.y * w0.y + nv.z * w0.z + nv.w * w0.w;
            a1 += nv.x * w1.x + nv.y * w1.y + nv.z * w1.z + nv.w * w1.w;
        }
        long base = (rowbase + row) * 16 + o0;
        NSP[base] = a0;
        NSP[base + 1] = a1;
    }
}

// ---------------------------------------------------------------------------
// Kernel 2: adj transpose (one-time, 256KB). adjT[j][i] = adj[i][j]
// ---------------------------------------------------------------------------
__global__ __launch_bounds__(256) void transpose_kernel(
    const float* __restrict__ adj, float* __restrict__ adjT)
{
    __shared__ float tile[32][33];
    const int tid = threadIdx.x;
    const int bx = blockIdx.x & 7, by = blockIdx.x >> 3;
    const int lx = tid & 31, ly = (tid >> 5) * 4;
#pragma unroll
    for (int r = 0; r < 4; r++)
        tile[ly + r][lx] = adj[(long)(by * 32 + ly + r) * 256 + bx * 32 + lx];
    __syncthreads();
#pragma unroll
    for (int r = 0; r < 4; r++)
        adjT[(long)(bx * 32 + ly + r) * 256 + by * 32 + lx] = tile[lx][ly + r];
}

// ---------------------------------------------------------------------------
// Kernel 3: AX[t,i,o] = b_in[o] + sum_j adj[i,j] * NSP[t,j,o]
// Grid 256 (t), block 256 (i = tid). NSP tile staged in LDS (broadcast reads).
// ---------------------------------------------------------------------------
__global__ __launch_bounds__(256) void aggx_kernel(
    const float* __restrict__ adjT, const float* __restrict__ NSP,
    const float* __restrict__ b_in, float* __restrict__ AX)
{
    __shared__ float4 nsp_s[256 * 4];
    const int tid = threadIdx.x;
    const int t = blockIdx.x;
    {
        const float4* g = (const float4*)(NSP + (long)t * 4096);
#pragma unroll
        for (int i = 0; i < 4; i++) nsp_s[tid + i * 256] = g[tid + i * 256];
    }
    __syncthreads();

    float4 acc[4];
#pragma unroll
    for (int p = 0; p < 4; p++) acc[p] = ((const float4*)b_in)[p];

    const float* arow = adjT + tid;
    float a[8], an[8];
#pragma unroll
    for (int m = 0; m < 8; m++) an[m] = arow[m * 256];
    for (int j0 = 0; j0 < 256; j0 += 8) {
#pragma unroll
        for (int m = 0; m < 8; m++) a[m] = an[m];
        if (j0 + 8 < 256) {
#pragma unroll
            for (int m = 0; m < 8; m++) an[m] = arow[(j0 + 8 + m) * 256];
        }
#pragma unroll
        for (int m = 0; m < 8; m++) {
            float av = a[m];
#pragma unroll
            for (int p = 0; p < 4; p++) {
                float4 nv = nsp_s[(j0 + m) * 4 + p];
                acc[p].x += av * nv.x; acc[p].y += av * nv.y;
                acc[p].z += av * nv.z; acc[p].w += av * nv.w;
            }
        }
    }
    float4* out = (float4*)(AX + (long)t * 4096 + tid * 16);
#pragma unroll
    for (int p = 0; p < 4; p++) out[p] = acc[p];
}

// ---------------------------------------------------------------------------
// Kernel 4: LSTM scan. One wave (64 threads) per batch element, NO barriers.
// lane = o*4+s: o in [0,16) = gate output, s = k-slice. h kept in LDS,
// z broadcast via v_readlane. Conflict-free interleaved h read layout.
// ---------------------------------------------------------------------------
__global__ __launch_bounds__(64) void lstm_kernel(
    const float* __restrict__ AX, const float* __restrict__ Win,
    const float* __restrict__ Wout, const float* __restrict__ b_out,
    float* __restrict__ HS)
{
    __shared__ __align__(16) float h_lds[128];

    const int lane = threadIdx.x;
    const int b = blockIdx.x;
    const int o = lane >> 2;
    const int s = lane & 3;
    const int g_o = o >> 2, q_o = o & 3;

    // wh[m*4+j] = Win_h[k][o] with k = m*16 + s*4 + j  (conflict-free h4 reads)
    float wh[32];
#pragma unroll
    for (int m = 0; m < 8; m++)
#pragma unroll
        for (int j = 0; j < 4; j++)
            wh[m * 4 + j] = Win[g_o * 1024 + 512 + (m * 16 + s * 4 + j) * 4 + q_o];

    float wo[4][4][2];
    float bo[4][2];
#pragma unroll
    for (int g = 0; g < 4; g++) {
#pragma unroll
        for (int h2 = 0; h2 < 2; h2++) bo[g][h2] = b_out[g * 128 + lane + 64 * h2];
#pragma unroll
        for (int q = 0; q < 4; q++)
#pragma unroll
            for (int h2 = 0; h2 < 2; h2++)
                wo[g][q][h2] = Wout[(g * 4 + q) * 128 + lane + 64 * h2];
    }

    float c[2] = {0.f, 0.f};
    h_lds[lane] = 0.f;
    h_lds[lane + 64] = 0.f;
    asm volatile("s_waitcnt lgkmcnt(0)" ::: "memory");

    float ax_cur = AX[(long)b * 16 + o];
    const float4* h4 = (const float4*)h_lds;

    for (int t = 0; t < T_DIM; t++) {
        // zpre partial over k = {m*16 + s*4 + j}: 4 parallel chains
        float4 hv[8];
#pragma unroll
        for (int m = 0; m < 8; m++) hv[m] = h4[m * 4 + s];
        float a0 = 0.f, a1 = 0.f, a2 = 0.f, a3 = 0.f;
#pragma unroll
        for (int m = 0; m < 8; m += 4) {
            a0 += hv[m].x * wh[m*4] + hv[m].y * wh[m*4+1] + hv[m].z * wh[m*4+2] + hv[m].w * wh[m*4+3];
            a1 += hv[m+1].x * wh[m*4+4] + hv[m+1].y * wh[m*4+5] + hv[m+1].z * wh[m*4+6] + hv[m+1].w * wh[m*4+7];
            a2 += hv[m+2].x * wh[m*4+8] + hv[m+2].y * wh[m*4+9] + hv[m+2].z * wh[m*4+10] + hv[m+2].w * wh[m*4+11];
            a3 += hv[m+3].x * wh[m*4+12] + hv[m+3].y * wh[m*4+13] + hv[m+3].z * wh[m*4+14] + hv[m+3].w * wh[m*4+15];
        }
        float acc = (a0 + a1) + (a2 + a3);
        acc += __shfl_xor(acc, 1);
        acc += __shfl_xor(acc, 2);
        float zv = tanhf_fast(acc + ax_cur);

        if (t + 1 < T_DIM)
            ax_cur = AX[(long)(t + 1) * (B_DIM * 16) + (long)b * 16 + o];

        // broadcast all 16 z values via readlane (z[oo] lives at lane 4*oo)
        unsigned zb = __float_as_uint(zv);
        float z[16];
#pragma unroll
        for (int oo = 0; oo < 16; oo++)
            z[oo] = __uint_as_float(__builtin_amdgcn_readlane(zb, oo * 4));

        float hv_out[2];
#pragma unroll
        for (int h2 = 0; h2 < 2; h2++) {
            float gp_f = bo[0][h2] + z[0]*wo[0][0][h2] + z[1]*wo[0][1][h2] + z[2]*wo[0][2][h2] + z[3]*wo[0][3][h2];
            float gp_i = bo[1][h2] + z[4]*wo[1][0][h2] + z[5]*wo[1][1][h2] + z[6]*wo[1][2][h2] + z[7]*wo[1][3][h2];
            float gp_g = bo[2][h2] + z[8]*wo[2][0][h2] + z[9]*wo[2][1][h2] + z[10]*wo[2][2][h2] + z[11]*wo[2][3][h2];
            float gp_o = bo[3][h2] + z[12]*wo[3][0][h2] + z[13]*wo[3][1][h2] + z[14]*wo[3][2][h2] + z[15]*wo[3][3][h2];
            float fg = sigf(gp_f);
            float ig = sigf(gp_i);
            float gg = tanhf_fast(gp_g);
            float og = sigf(gp_o);
            c[h2] = fg * c[h2] + ig * gg;
            hv_out[h2] = og * tanhf_fast(c[h2]);
        }

        h_lds[lane] = hv_out[0];
        h_lds[lane + 64] = hv_out[1];
        asm volatile("s_waitcnt lgkmcnt(0)" ::: "memory");

        long outbase = (long)t * (B_DIM * H_DIM) + (long)b * H_DIM;
        HS[outbase + lane] = hv_out[0];
        HS[outbase + lane + 64] = hv_out[1];
    }
}

// ---------------------------------------------------------------------------
// Kernel 5: tag head + log_softmax. Block 256 = 8 rows x 32 tags.
// ---------------------------------------------------------------------------
__global__ __launch_bounds__(256) void head_kernel(
    const float* __restrict__ HS, const float* __restrict__ Wtag,
    const float* __restrict__ btag, float* __restrict__ OUT)
{
    __shared__ float wt[128 * 32];
    const int tid = threadIdx.x;
    {
        float4* wt4 = (float4*)wt;
        const float4* wg = (const float4*)Wtag;
#pragma unroll
        for (int i = 0; i < 4; i++) wt4[tid + i * 256] = wg[tid + i * 256];
    }
    __syncthreads();

    long row = (long)blockIdx.x * 8 + (tid >> 5);
    int tag = tid & 31;
    const float4* xr = (const float4*)(HS + row * 128);
    float acc = btag[tag];
#pragma unroll 8
    for (int k4 = 0; k4 < 32; k4++) {
        float4 xv = xr[k4];
        acc += xv.x * wt[(k4 * 4 + 0) * 32 + tag] + xv.y * wt[(k4 * 4 + 1) * 32 + tag]
             + xv.z * wt[(k4 * 4 + 2) * 32 + tag] + xv.w * wt[(k4 * 4 + 3) * 32 + tag];
    }
    float m = acc;
#pragma unroll
    for (int d = 16; d >= 1; d >>= 1) m = fmaxf(m, __shfl_xor(m, d));
    float e = __expf(acc - m);
#pragma unroll
    for (int d = 16; d >= 1; d >>= 1) e += __shfl_xor(e, d);
    OUT[row * 32 + tag] = acc - m - __logf(e);
}

// ---------------------------------------------------------------------------
extern "C" void kernel_launch(void* const* d_in, const int* in_sizes, int n_in,
                              void* d_out, int out_size, void* d_ws, size_t ws_size,
                              hipStream_t stream)
{
    const float* X    = (const float*)d_in[0];   // [T,B,F]
    const float* adj  = (const float*)d_in[1];   // [B,B]
    const float* W1   = (const float*)d_in[2];   // [F,H1]
    const float* b1   = (const float*)d_in[3];
    const float* W2   = (const float*)d_in[4];   // [H1,H]
    const float* b2   = (const float*)d_in[5];
    const float* Win  = (const float*)d_in[6];   // [4,F+H,Q]
    const float* b_in = (const float*)d_in[7];   // [4,Q]
    const float* Wout = (const float*)d_in[8];   // [4,Q,H]
    const float* bout = (const float*)d_in[9];   // [4,H]
    const float* Wtag = (const float*)d_in[10];  // [H,TAGS]
    const float* btag = (const float*)d_in[11];
    float* OUT = (float*)d_out;

    float* ws = (float*)d_ws;
    float* NSP  = ws;                    // [T,B,16]  1,048,576 f
    float* adjT = ws + 1048576;          // [B,B]        65,536 f
    float* AX   = ws + 1114112;          // [T,B,16]  1,048,576 f
    float* HS   = ws + 2162688;          // [T,B,H]   8,388,608 f

    mlp_kernel<<<dim3(TB / 32), dim3(256), 0, stream>>>(X, W1, b1, W2, b2, Win, NSP);
    transpose_kernel<<<dim3(64), dim3(256), 0, stream>>>(adj, adjT);
    aggx_kernel<<<dim3(256), dim3(256), 0, stream>>>(adjT, NSP, b_in, AX);
    lstm_kernel<<<dim3(B_DIM), dim3(64), 0, stream>>>(AX, Win, Wout, bout, HS);
    head_kernel<<<dim3(TB / 8), dim3(256), 0, stream>>>(HS, Wtag, btag, OUT);
}

// Round 4
// 372.157 us; speedup vs baseline: 1.3698x; 1.0304x over previous
//
#include <hip/hip_runtime.h>
#include <hip/hip_bf16.h>

// Problem dims (fixed)
#define T_DIM 256
#define B_DIM 256
#define F_DIM 128
#define H1_DIM 256
#define H_DIM 128
#define Q_DIM 4
#define TAGS 32
#define TB (T_DIM * B_DIM)   // 65536 rows

__device__ __forceinline__ float tanhf_fast(float x) {
    float e = __expf(2.0f * x);
    return 1.0f - 2.0f / (e + 1.0f);
}
__device__ __forceinline__ float sigf(float x) {
    return 1.0f / (1.0f + __expf(-x));
}

// DPP cross-lane add within quad: CTRL=0xB1 -> lane^1, CTRL=0x4E -> lane^2
template<int CTRL>
__device__ __forceinline__ float dpp_xadd(float x) {
    int t = __builtin_amdgcn_update_dpp(0, __float_as_int(x), CTRL, 0xF, 0xF, true);
    return x + __int_as_float(t);
}

// ---------------------------------------------------------------------------
// Kernel 1: per-node MLP + fused Win_x projection.
// NSP[row, o] = tanh(tanh(X@W1+b1)@W2+b2) @ Win_x[:,o]     (o = g*4+q, 16 outs)
// Block: 256 threads, 32 rows per block. Grid: TB/32 = 2048.
// ---------------------------------------------------------------------------
__global__ __launch_bounds__(256) void mlp_kernel(
    const float* __restrict__ X, const float* __restrict__ W1,
    const float* __restrict__ b1, const float* __restrict__ W2,
    const float* __restrict__ b2, const float* __restrict__ Win,
    float* __restrict__ NSP)
{
    __shared__ float smemA[32 * 132];   // xs [32][128] then nss [32][132]
    __shared__ float smemB[32 * 256];   // a1s [32][256] then wxsT [16][132]
    const int tid = threadIdx.x;
    const long rowbase = (long)blockIdx.x * 32;

    // stage X tile (32 x 128) into smemA (stride 128)
    {
        const float4* Xg = (const float4*)(X + rowbase * 128);
        float4* xs4 = (float4*)smemA;
#pragma unroll
        for (int i = 0; i < 4; i++) xs4[tid + i * 256] = Xg[tid + i * 256];
    }
    __syncthreads();

    // Phase A: a1 = tanh(x @ W1 + b1)   [32 x 256] -> smemB
    {
        const int rg = tid >> 6;
        const int c0 = tid & 63;
        float acc[8][4];
#pragma unroll
        for (int r = 0; r < 8; r++)
#pragma unroll
            for (int j = 0; j < 4; j++) acc[r][j] = 0.0f;

        const float4* xs4 = (const float4*)smemA;
        for (int k4 = 0; k4 < 32; k4++) {
            float4 xv[8];
#pragma unroll
            for (int r = 0; r < 8; r++) xv[r] = xs4[(rg * 8 + r) * 32 + k4];
            float wv[4][4];
#pragma unroll
            for (int kk = 0; kk < 4; kk++)
#pragma unroll
                for (int j = 0; j < 4; j++)
                    wv[kk][j] = W1[(k4 * 4 + kk) * 256 + c0 + 64 * j];
#pragma unroll
            for (int r = 0; r < 8; r++)
#pragma unroll
                for (int j = 0; j < 4; j++)
                    acc[r][j] += xv[r].x * wv[0][j] + xv[r].y * wv[1][j]
                               + xv[r].z * wv[2][j] + xv[r].w * wv[3][j];
        }
#pragma unroll
        for (int r = 0; r < 8; r++)
#pragma unroll
            for (int j = 0; j < 4; j++) {
                int c = c0 + 64 * j;
                smemB[(rg * 8 + r) * 256 + c] = tanhf_fast(acc[r][j] + b1[c]);
            }
    }
    __syncthreads();

    // Phase B: ns = tanh(a1 @ W2 + b2)   [32 x 128] -> nss in smemA (stride 132)
    {
        const int rg = tid >> 6;
        const int c0 = tid & 63;
        float acc[8][2];
#pragma unroll
        for (int r = 0; r < 8; r++)
#pragma unroll
            for (int j = 0; j < 2; j++) acc[r][j] = 0.0f;

        const float4* a1s4 = (const float4*)smemB;
        for (int k4 = 0; k4 < 64; k4++) {
            float4 av[8];
#pragma unroll
            for (int r = 0; r < 8; r++) av[r] = a1s4[(rg * 8 + r) * 64 + k4];
            float wv[4][2];
#pragma unroll
            for (int kk = 0; kk < 4; kk++)
#pragma unroll
                for (int j = 0; j < 2; j++)
                    wv[kk][j] = W2[(k4 * 4 + kk) * 128 + c0 + 64 * j];
#pragma unroll
            for (int r = 0; r < 8; r++)
#pragma unroll
                for (int j = 0; j < 2; j++)
                    acc[r][j] += av[r].x * wv[0][j] + av[r].y * wv[1][j]
                               + av[r].z * wv[2][j] + av[r].w * wv[3][j];
        }
        // write ns into nss (smemA, stride 132) — disjoint from smemB reads
#pragma unroll
        for (int r = 0; r < 8; r++)
#pragma unroll
            for (int j = 0; j < 2; j++) {
                int c = c0 + 64 * j;
                smemA[(rg * 8 + r) * 132 + c] = tanhf_fast(acc[r][j] + b2[c]);
            }
    }
    __syncthreads();   // all Phase-B a1s reads done -> can overwrite smemB

    // stage Win_x transposed: wxsT[o][f] = Win[g][f][q], o=g*4+q  (16 x 132)
    for (int idx = tid; idx < 2048; idx += 256) {
        int o = idx >> 7, f = idx & 127;
        smemB[o * 132 + f] = Win[(o >> 2) * 1024 + f * 4 + (o & 3)];
    }
    __syncthreads();

    // NSP gemm: 32 rows x 16 o, 2 o per thread
    {
        const int row = tid >> 3;
        const int o0 = (tid & 7) * 2;
        const float4* nss4 = (const float4*)smemA;
        const float4* wx4 = (const float4*)smemB;
        float a0 = 0.f, a1 = 0.f;
#pragma unroll
        for (int f4 = 0; f4 < 32; f4++) {
            float4 nv = nss4[row * 33 + f4];
            float4 w0 = wx4[o0 * 33 + f4];
            float4 w1 = wx4[(o0 + 1) * 33 + f4];
            a0 += nv.x * w0.x + nv.y * w0.y + nv.z * w0.z + nv.w * w0.w;
            a1 += nv.x * w1.x + nv.y * w1.y + nv.z * w1.z + nv.w * w1.w;
        }
        long base = (rowbase + row) * 16 + o0;
        NSP[base] = a0;
        NSP[base + 1] = a1;
    }
}

// ---------------------------------------------------------------------------
// Kernel 2: adj transpose (one-time, 256KB). adjT[j][i] = adj[i][j]
// ---------------------------------------------------------------------------
__global__ __launch_bounds__(256) void transpose_kernel(
    const float* __restrict__ adj, float* __restrict__ adjT)
{
    __shared__ float tile[32][33];
    const int tid = threadIdx.x;
    const int bx = blockIdx.x & 7, by = blockIdx.x >> 3;
    const int lx = tid & 31, ly = (tid >> 5) * 4;
#pragma unroll
    for (int r = 0; r < 4; r++)
        tile[ly + r][lx] = adj[(long)(by * 32 + ly + r) * 256 + bx * 32 + lx];
    __syncthreads();
#pragma unroll
    for (int r = 0; r < 4; r++)
        adjT[(long)(bx * 32 + ly + r) * 256 + by * 32 + lx] = tile[lx][ly + r];
}

// ---------------------------------------------------------------------------
// Kernel 3: AX[t,i,o] = b_in[o] + sum_j adj[i,j] * NSP[t,j,o]
// Grid 256 (t), block 256 (i = tid). NSP tile staged in LDS (broadcast reads).
// ---------------------------------------------------------------------------
__global__ __launch_bounds__(256) void aggx_kernel(
    const float* __restrict__ adjT, const float* __restrict__ NSP,
    const float* __restrict__ b_in, float* __restrict__ AX)
{
    __shared__ float4 nsp_s[256 * 4];
    const int tid = threadIdx.x;
    const int t = blockIdx.x;
    {
        const float4* g = (const float4*)(NSP + (long)t * 4096);
#pragma unroll
        for (int i = 0; i < 4; i++) nsp_s[tid + i * 256] = g[tid + i * 256];
    }
    __syncthreads();

    float4 acc[4];
#pragma unroll
    for (int p = 0; p < 4; p++) acc[p] = ((const float4*)b_in)[p];

    const float* arow = adjT + tid;
    float a[8], an[8];
#pragma unroll
    for (int m = 0; m < 8; m++) an[m] = arow[m * 256];
    for (int j0 = 0; j0 < 256; j0 += 8) {
#pragma unroll
        for (int m = 0; m < 8; m++) a[m] = an[m];
        if (j0 + 8 < 256) {
#pragma unroll
            for (int m = 0; m < 8; m++) an[m] = arow[(j0 + 8 + m) * 256];
        }
#pragma unroll
        for (int m = 0; m < 8; m++) {
            float av = a[m];
#pragma unroll
            for (int p = 0; p < 4; p++) {
                float4 nv = nsp_s[(j0 + m) * 4 + p];
                acc[p].x += av * nv.x; acc[p].y += av * nv.y;
                acc[p].z += av * nv.z; acc[p].w += av * nv.w;
            }
        }
    }
    float4* out = (float4*)(AX + (long)t * 4096 + tid * 16);
#pragma unroll
    for (int p = 0; p < 4; p++) out[p] = acc[p];
}

// ---------------------------------------------------------------------------
// Kernel 4: LSTM scan. One wave (64 threads) per batch element, NO barriers,
// NO spills: __launch_bounds__(64,1) gives the full VGPR file to the wave.
// lane = o*4+s: o in [0,16) = gate output, s = k-slice. h kept in LDS
// (DS ops are in-order per wave -> no explicit waitcnt needed),
// z reduced via DPP quad-perm adds, broadcast via v_readlane.
// ---------------------------------------------------------------------------
__global__ __launch_bounds__(64, 1) void lstm_kernel(
    const float* __restrict__ AX, const float* __restrict__ Win,
    const float* __restrict__ Wout, const float* __restrict__ b_out,
    float* __restrict__ HS)
{
    __shared__ __align__(16) float h_lds[128];

    const int lane = threadIdx.x;
    const int b = blockIdx.x;
    const int o = lane >> 2;
    const int s = lane & 3;
    const int g_o = o >> 2, q_o = o & 3;

    // wh[m*4+j] = Win_h[k][o] with k = m*16 + s*4 + j  (conflict-free h4 reads)
    float wh[32];
#pragma unroll
    for (int m = 0; m < 8; m++)
#pragma unroll
        for (int j = 0; j < 4; j++)
            wh[m * 4 + j] = Win[g_o * 1024 + 512 + (m * 16 + s * 4 + j) * 4 + q_o];

    float wo[4][4][2];
    float bo[4][2];
#pragma unroll
    for (int g = 0; g < 4; g++) {
#pragma unroll
        for (int h2 = 0; h2 < 2; h2++) bo[g][h2] = b_out[g * 128 + lane + 64 * h2];
#pragma unroll
        for (int q = 0; q < 4; q++)
#pragma unroll
            for (int h2 = 0; h2 < 2; h2++)
                wo[g][q][h2] = Wout[(g * 4 + q) * 128 + lane + 64 * h2];
    }

    float c[2] = {0.f, 0.f};
    h_lds[lane] = 0.f;
    h_lds[lane + 64] = 0.f;
    // single wave, DS in-order: lanes see the zero-init when they read below

    // distance-2 AX prefetch pipeline
    float ax_cur = AX[(long)b * 16 + o];
    float ax_nxt = AX[(long)(B_DIM * 16) + (long)b * 16 + o];

    const float4* h4 = (const float4*)h_lds;

    for (int t = 0; t < T_DIM; t++) {
        // zpre partial over k = {m*16 + s*4 + j}: 4 parallel chains
        float4 hv[8];
#pragma unroll
        for (int m = 0; m < 8; m++) hv[m] = h4[m * 4 + s];
        float a0 = 0.f, a1 = 0.f, a2 = 0.f, a3 = 0.f;
#pragma unroll
        for (int m = 0; m < 8; m += 4) {
            a0 += hv[m].x * wh[m*4] + hv[m].y * wh[m*4+1] + hv[m].z * wh[m*4+2] + hv[m].w * wh[m*4+3];
            a1 += hv[m+1].x * wh[m*4+4] + hv[m+1].y * wh[m*4+5] + hv[m+1].z * wh[m*4+6] + hv[m+1].w * wh[m*4+7];
            a2 += hv[m+2].x * wh[m*4+8] + hv[m+2].y * wh[m*4+9] + hv[m+2].z * wh[m*4+10] + hv[m+2].w * wh[m*4+11];
            a3 += hv[m+3].x * wh[m*4+12] + hv[m+3].y * wh[m*4+13] + hv[m+3].z * wh[m*4+14] + hv[m+3].w * wh[m*4+15];
        }
        float acc = (a0 + a1) + (a2 + a3);
        acc = dpp_xadd<0xB1>(acc);   // + lane^1
        acc = dpp_xadd<0x4E>(acc);   // + lane^2
        float zv = tanhf_fast(acc + ax_cur);

        // rotate distance-2 prefetch
        {
            int tp = t + 2;
            if (tp > T_DIM - 1) tp = T_DIM - 1;
            ax_cur = ax_nxt;
            ax_nxt = AX[(long)tp * (B_DIM * 16) + (long)b * 16 + o];
        }

        // broadcast all 16 z values via readlane (z[oo] lives at lane 4*oo)
        unsigned zb = __float_as_uint(zv);
        float z[16];
#pragma unroll
        for (int oo = 0; oo < 16; oo++)
            z[oo] = __uint_as_float(__builtin_amdgcn_readlane(zb, oo * 4));

        float hv_out[2];
#pragma unroll
        for (int h2 = 0; h2 < 2; h2++) {
            float gp_f = bo[0][h2] + z[0]*wo[0][0][h2] + z[1]*wo[0][1][h2] + z[2]*wo[0][2][h2] + z[3]*wo[0][3][h2];
            float gp_i = bo[1][h2] + z[4]*wo[1][0][h2] + z[5]*wo[1][1][h2] + z[6]*wo[1][2][h2] + z[7]*wo[1][3][h2];
            float gp_g = bo[2][h2] + z[8]*wo[2][0][h2] + z[9]*wo[2][1][h2] + z[10]*wo[2][2][h2] + z[11]*wo[2][3][h2];
            float gp_o = bo[3][h2] + z[12]*wo[3][0][h2] + z[13]*wo[3][1][h2] + z[14]*wo[3][2][h2] + z[15]*wo[3][3][h2];
            float fg = sigf(gp_f);
            float ig = sigf(gp_i);
            float gg = tanhf_fast(gp_g);
            float og = sigf(gp_o);
            c[h2] = fg * c[h2] + ig * gg;
            hv_out[h2] = og * tanhf_fast(c[h2]);
        }

        h_lds[lane] = hv_out[0];
        h_lds[lane + 64] = hv_out[1];
        // no explicit waitcnt: next iteration's ds_reads are ordered after
        // these ds_writes in the per-wave DS pipeline

        long outbase = (long)t * (B_DIM * H_DIM) + (long)b * H_DIM;
        HS[outbase + lane] = hv_out[0];
        HS[outbase + lane + 64] = hv_out[1];
    }
}

// ---------------------------------------------------------------------------
// Kernel 5: tag head + log_softmax. Block 256 = 8 rows x 32 tags.
// ---------------------------------------------------------------------------
__global__ __launch_bounds__(256) void head_kernel(
    const float* __restrict__ HS, const float* __restrict__ Wtag,
    const float* __restrict__ btag, float* __restrict__ OUT)
{
    __shared__ float wt[128 * 32];
    const int tid = threadIdx.x;
    {
        float4* wt4 = (float4*)wt;
        const float4* wg = (const float4*)Wtag;
#pragma unroll
        for (int i = 0; i < 4; i++) wt4[tid + i * 256] = wg[tid + i * 256];
    }
    __syncthreads();

    long row = (long)blockIdx.x * 8 + (tid >> 5);
    int tag = tid & 31;
    const float4* xr = (const float4*)(HS + row * 128);
    float acc = btag[tag];
#pragma unroll 8
    for (int k4 = 0; k4 < 32; k4++) {
        float4 xv = xr[k4];
        acc += xv.x * wt[(k4 * 4 + 0) * 32 + tag] + xv.y * wt[(k4 * 4 + 1) * 32 + tag]
             + xv.z * wt[(k4 * 4 + 2) * 32 + tag] + xv.w * wt[(k4 * 4 + 3) * 32 + tag];
    }
    float m = acc;
#pragma unroll
    for (int d = 16; d >= 1; d >>= 1) m = fmaxf(m, __shfl_xor(m, d));
    float e = __expf(acc - m);
#pragma unroll
    for (int d = 16; d >= 1; d >>= 1) e += __shfl_xor(e, d);
    OUT[row * 32 + tag] = acc - m - __logf(e);
}

// ---------------------------------------------------------------------------
extern "C" void kernel_launch(void* const* d_in, const int* in_sizes, int n_in,
                              void* d_out, int out_size, void* d_ws, size_t ws_size,
                              hipStream_t stream)
{
    const float* X    = (const float*)d_in[0];   // [T,B,F]
    const float* adj  = (const float*)d_in[1];   // [B,B]
    const float* W1   = (const float*)d_in[2];   // [F,H1]
    const float* b1   = (const float*)d_in[3];
    const float* W2   = (const float*)d_in[4];   // [H1,H]
    const float* b2   = (const float*)d_in[5];
    const float* Win  = (const float*)d_in[6];   // [4,F+H,Q]
    const float* b_in = (const float*)d_in[7];   // [4,Q]
    const float* Wout = (const float*)d_in[8];   // [4,Q,H]
    const float* bout = (const float*)d_in[9];   // [4,H]
    const float* Wtag = (const float*)d_in[10];  // [H,TAGS]
    const float* btag = (const float*)d_in[11];
    float* OUT = (float*)d_out;

    float* ws = (float*)d_ws;
    float* NSP  = ws;                    // [T,B,16]  1,048,576 f
    float* adjT = ws + 1048576;          // [B,B]        65,536 f
    float* AX   = ws + 1114112;          // [T,B,16]  1,048,576 f
    float* HS   = ws + 2162688;          // [T,B,H]   8,388,608 f

    mlp_kernel<<<dim3(TB / 32), dim3(256), 0, stream>>>(X, W1, b1, W2, b2, Win, NSP);
    transpose_kernel<<<dim3(64), dim3(256), 0, stream>>>(adj, adjT);
    aggx_kernel<<<dim3(256), dim3(256), 0, stream>>>(adjT, NSP, b_in, AX);
    lstm_kernel<<<dim3(B_DIM), dim3(64), 0, stream>>>(AX, Win, Wout, bout, HS);
    head_kernel<<<dim3(TB / 8), dim3(256), 0, stream>>>(HS, Wtag, btag, OUT);
}

// Round 5
// 365.113 us; speedup vs baseline: 1.3963x; 1.0193x over previous
//
#include <hip/hip_runtime.h>
#include <hip/hip_bf16.h>

// Problem dims (fixed)
#define T_DIM 256
#define B_DIM 256
#define F_DIM 128
#define H1_DIM 256
#define H_DIM 128
#define Q_DIM 4
#define TAGS 32
#define TB (T_DIM * B_DIM)   // 65536 rows

__device__ __forceinline__ float tanhf_fast(float x) {
    float e = __expf(2.0f * x);
    return 1.0f - 2.0f / (e + 1.0f);
}
__device__ __forceinline__ float sigf(float x) {
    return 1.0f / (1.0f + __expf(-x));
}

// DPP cross-lane add within quad: CTRL=0xB1 -> lane^1, CTRL=0x4E -> lane^2
template<int CTRL>
__device__ __forceinline__ float dpp_xadd(float x) {
    int t = __builtin_amdgcn_update_dpp(0, __float_as_int(x), CTRL, 0xF, 0xF, true);
    return x + __int_as_float(t);
}

// ---------------------------------------------------------------------------
// Kernel 1: per-node MLP + fused Win_x projection.
// NSP[row, o] = tanh(tanh(X@W1+b1)@W2+b2) @ Win_x[:,o]     (o = g*4+q, 16 outs)
// Block: 256 threads, 32 rows per block. Grid: TB/32 = 2048.
// Columns assigned CONTIGUOUSLY per thread so W loads are float4/float2.
// ---------------------------------------------------------------------------
__global__ __launch_bounds__(256) void mlp_kernel(
    const float* __restrict__ X, const float* __restrict__ W1,
    const float* __restrict__ b1, const float* __restrict__ W2,
    const float* __restrict__ b2, const float* __restrict__ Win,
    float* __restrict__ NSP)
{
    __shared__ float smemA[32 * 132];   // xs [32][128] then nss [32][132]
    __shared__ float smemB[32 * 256];   // a1s [32][256] then wxsT [16][132]
    const int tid = threadIdx.x;
    const long rowbase = (long)blockIdx.x * 32;

    // stage X tile (32 x 128) into smemA (stride 128)
    {
        const float4* Xg = (const float4*)(X + rowbase * 128);
        float4* xs4 = (float4*)smemA;
#pragma unroll
        for (int i = 0; i < 4; i++) xs4[tid + i * 256] = Xg[tid + i * 256];
    }
    __syncthreads();

    // Phase A: a1 = tanh(x @ W1 + b1)   [32 x 256] -> smemB
    // thread (rg, c0): rows rg*8..+7, cols 4*c0..4*c0+3
    {
        const int rg = tid >> 6;
        const int c0 = tid & 63;
        float4 acc[8];
#pragma unroll
        for (int r = 0; r < 8; r++) acc[r] = make_float4(0.f, 0.f, 0.f, 0.f);

        const float4* xs4 = (const float4*)smemA;
        for (int k4 = 0; k4 < 32; k4++) {
            float4 xv[8];
#pragma unroll
            for (int r = 0; r < 8; r++) xv[r] = xs4[(rg * 8 + r) * 32 + k4];
            float4 wv[4];
#pragma unroll
            for (int kk = 0; kk < 4; kk++)
                wv[kk] = *(const float4*)(W1 + (k4 * 4 + kk) * 256 + c0 * 4);
#pragma unroll
            for (int r = 0; r < 8; r++) {
                acc[r].x += xv[r].x*wv[0].x + xv[r].y*wv[1].x + xv[r].z*wv[2].x + xv[r].w*wv[3].x;
                acc[r].y += xv[r].x*wv[0].y + xv[r].y*wv[1].y + xv[r].z*wv[2].y + xv[r].w*wv[3].y;
                acc[r].z += xv[r].x*wv[0].z + xv[r].y*wv[1].z + xv[r].z*wv[2].z + xv[r].w*wv[3].z;
                acc[r].w += xv[r].x*wv[0].w + xv[r].y*wv[1].w + xv[r].z*wv[2].w + xv[r].w*wv[3].w;
            }
        }
        float4 bv = *(const float4*)(b1 + c0 * 4);
#pragma unroll
        for (int r = 0; r < 8; r++) {
            float4 out;
            out.x = tanhf_fast(acc[r].x + bv.x);
            out.y = tanhf_fast(acc[r].y + bv.y);
            out.z = tanhf_fast(acc[r].z + bv.z);
            out.w = tanhf_fast(acc[r].w + bv.w);
            *(float4*)(&smemB[(rg * 8 + r) * 256 + c0 * 4]) = out;
        }
    }
    __syncthreads();

    // Phase B: ns = tanh(a1 @ W2 + b2)   [32 x 128] -> nss in smemA (stride 132)
    // thread (rg, c0): rows rg*8..+7, cols 2*c0, 2*c0+1
    {
        const int rg = tid >> 6;
        const int c0 = tid & 63;
        float2 acc[8];
#pragma unroll
        for (int r = 0; r < 8; r++) acc[r] = make_float2(0.f, 0.f);

        const float4* a1s4 = (const float4*)smemB;
        for (int k4 = 0; k4 < 64; k4++) {
            float4 av[8];
#pragma unroll
            for (int r = 0; r < 8; r++) av[r] = a1s4[(rg * 8 + r) * 64 + k4];
            float2 wv[4];
#pragma unroll
            for (int kk = 0; kk < 4; kk++)
                wv[kk] = *(const float2*)(W2 + (k4 * 4 + kk) * 128 + c0 * 2);
#pragma unroll
            for (int r = 0; r < 8; r++) {
                acc[r].x += av[r].x*wv[0].x + av[r].y*wv[1].x + av[r].z*wv[2].x + av[r].w*wv[3].x;
                acc[r].y += av[r].x*wv[0].y + av[r].y*wv[1].y + av[r].z*wv[2].y + av[r].w*wv[3].y;
            }
        }
        float2 bv = *(const float2*)(b2 + c0 * 2);
#pragma unroll
        for (int r = 0; r < 8; r++) {
            float2 out;
            out.x = tanhf_fast(acc[r].x + bv.x);
            out.y = tanhf_fast(acc[r].y + bv.y);
            *(float2*)(&smemA[(rg * 8 + r) * 132 + c0 * 2]) = out;
        }
    }
    __syncthreads();   // all Phase-B a1s reads done -> can overwrite smemB

    // stage Win_x transposed: wxsT[o][f] = Win[g][f][q], o=g*4+q  (16 x 132)
    for (int idx = tid; idx < 2048; idx += 256) {
        int o = idx >> 7, f = idx & 127;
        smemB[o * 132 + f] = Win[(o >> 2) * 1024 + f * 4 + (o & 3)];
    }
    __syncthreads();

    // NSP gemm: 32 rows x 16 o, 2 o per thread
    {
        const int row = tid >> 3;
        const int o0 = (tid & 7) * 2;
        const float4* nss4 = (const float4*)smemA;
        const float4* wx4 = (const float4*)smemB;
        float a0 = 0.f, a1 = 0.f;
#pragma unroll
        for (int f4 = 0; f4 < 32; f4++) {
            float4 nv = nss4[row * 33 + f4];
            float4 w0 = wx4[o0 * 33 + f4];
            float4 w1 = wx4[(o0 + 1) * 33 + f4];
            a0 += nv.x * w0.x + nv.y * w0.y + nv.z * w0.z + nv.w * w0.w;
            a1 += nv.x * w1.x + nv.y * w1.y + nv.z * w1.z + nv.w * w1.w;
        }
        long base = (rowbase + row) * 16 + o0;
        NSP[base] = a0;
        NSP[base + 1] = a1;
    }
}

// ---------------------------------------------------------------------------
// Kernel 2: adj transpose (one-time, 256KB). adjT[j][i] = adj[i][j]
// ---------------------------------------------------------------------------
__global__ __launch_bounds__(256) void transpose_kernel(
    const float* __restrict__ adj, float* __restrict__ adjT)
{
    __shared__ float tile[32][33];
    const int tid = threadIdx.x;
    const int bx = blockIdx.x & 7, by = blockIdx.x >> 3;
    const int lx = tid & 31, ly = (tid >> 5) * 4;
#pragma unroll
    for (int r = 0; r < 4; r++)
        tile[ly + r][lx] = adj[(long)(by * 32 + ly + r) * 256 + bx * 32 + lx];
    __syncthreads();
#pragma unroll
    for (int r = 0; r < 4; r++)
        adjT[(long)(bx * 32 + ly + r) * 256 + by * 32 + lx] = tile[lx][ly + r];
}

// ---------------------------------------------------------------------------
// Kernel 3: AX[t,i,o] = b_in[o] + sum_j adj[i,j] * NSP[t,j,o]
// Grid 256 (t), block 256 (i = tid). NSP tile staged in LDS (broadcast reads).
// ---------------------------------------------------------------------------
__global__ __launch_bounds__(256) void aggx_kernel(
    const float* __restrict__ adjT, const float* __restrict__ NSP,
    const float* __restrict__ b_in, float* __restrict__ AX)
{
    __shared__ float4 nsp_s[256 * 4];
    const int tid = threadIdx.x;
    const int t = blockIdx.x;
    {
        const float4* g = (const float4*)(NSP + (long)t * 4096);
#pragma unroll
        for (int i = 0; i < 4; i++) nsp_s[tid + i * 256] = g[tid + i * 256];
    }
    __syncthreads();

    float4 acc[4];
#pragma unroll
    for (int p = 0; p < 4; p++) acc[p] = ((const float4*)b_in)[p];

    const float* arow = adjT + tid;
    float a[8], an[8];
#pragma unroll
    for (int m = 0; m < 8; m++) an[m] = arow[m * 256];
    for (int j0 = 0; j0 < 256; j0 += 8) {
#pragma unroll
        for (int m = 0; m < 8; m++) a[m] = an[m];
        if (j0 + 8 < 256) {
#pragma unroll
            for (int m = 0; m < 8; m++) an[m] = arow[(j0 + 8 + m) * 256];
        }
#pragma unroll
        for (int m = 0; m < 8; m++) {
            float av = a[m];
#pragma unroll
            for (int p = 0; p < 4; p++) {
                float4 nv = nsp_s[(j0 + m) * 4 + p];
                acc[p].x += av * nv.x; acc[p].y += av * nv.y;
                acc[p].z += av * nv.z; acc[p].w += av * nv.w;
            }
        }
    }
    float4* out = (float4*)(AX + (long)t * 4096 + tid * 16);
#pragma unroll
    for (int p = 0; p < 4; p++) out[p] = acc[p];
}

// ---------------------------------------------------------------------------
// Kernel 4: LSTM scan. One wave per batch element, NO barriers.
// amdgpu_waves_per_eu(1,1) forces the allocator to the full VGPR budget so
// wh/wo/bo live in registers (launch_bounds' 2nd arg alone left it at 64
// VGPRs -> per-iteration scratch spills, the round-4 bottleneck).
// ---------------------------------------------------------------------------
__global__ __attribute__((amdgpu_waves_per_eu(1, 1))) __launch_bounds__(64)
void lstm_kernel(
    const float* __restrict__ AX, const float* __restrict__ Win,
    const float* __restrict__ Wout, const float* __restrict__ b_out,
    float* __restrict__ HS)
{
    __shared__ __align__(16) float h_lds[128];

    const int lane = threadIdx.x;
    const int b = blockIdx.x;
    const int o = lane >> 2;
    const int s = lane & 3;
    const int g_o = o >> 2, q_o = o & 3;

    // wh[m*4+j] = Win_h[k][o] with k = m*16 + s*4 + j  (conflict-free h4 reads)
    float wh[32];
#pragma unroll
    for (int m = 0; m < 8; m++)
#pragma unroll
        for (int j = 0; j < 4; j++)
            wh[m * 4 + j] = Win[g_o * 1024 + 512 + (m * 16 + s * 4 + j) * 4 + q_o];

    float wo[4][4][2];
    float bo[4][2];
#pragma unroll
    for (int g = 0; g < 4; g++) {
#pragma unroll
        for (int h2 = 0; h2 < 2; h2++) bo[g][h2] = b_out[g * 128 + lane + 64 * h2];
#pragma unroll
        for (int q = 0; q < 4; q++)
#pragma unroll
            for (int h2 = 0; h2 < 2; h2++)
                wo[g][q][h2] = Wout[(g * 4 + q) * 128 + lane + 64 * h2];
    }

    float c[2] = {0.f, 0.f};
    h_lds[lane] = 0.f;
    h_lds[lane + 64] = 0.f;

    // distance-2 AX prefetch pipeline
    float ax_cur = AX[(long)b * 16 + o];
    float ax_nxt = AX[(long)(B_DIM * 16) + (long)b * 16 + o];

    const float4* h4 = (const float4*)h_lds;

    for (int t = 0; t < T_DIM; t++) {
        // zpre partial over k = {m*16 + s*4 + j}: 4 chains, 2 half-batches
        float a0 = 0.f, a1 = 0.f, a2 = 0.f, a3 = 0.f;
#pragma unroll
        for (int half = 0; half < 2; half++) {
            float4 hv[4];
#pragma unroll
            for (int m = 0; m < 4; m++) hv[m] = h4[(half * 4 + m) * 4 + s];
            const float* w = wh + half * 16;
            a0 += hv[0].x*w[0]  + hv[0].y*w[1]  + hv[0].z*w[2]  + hv[0].w*w[3];
            a1 += hv[1].x*w[4]  + hv[1].y*w[5]  + hv[1].z*w[6]  + hv[1].w*w[7];
            a2 += hv[2].x*w[8]  + hv[2].y*w[9]  + hv[2].z*w[10] + hv[2].w*w[11];
            a3 += hv[3].x*w[12] + hv[3].y*w[13] + hv[3].z*w[14] + hv[3].w*w[15];
        }
        float acc = (a0 + a1) + (a2 + a3);
        acc = dpp_xadd<0xB1>(acc);   // + lane^1
        acc = dpp_xadd<0x4E>(acc);   // + lane^2
        float zv = tanhf_fast(acc + ax_cur);

        // rotate distance-2 prefetch
        {
            int tp = t + 2;
            if (tp > T_DIM - 1) tp = T_DIM - 1;
            ax_cur = ax_nxt;
            ax_nxt = AX[(long)tp * (B_DIM * 16) + (long)b * 16 + o];
        }

        // broadcast all 16 z values via readlane (z[oo] lives at lane 4*oo)
        unsigned zb = __float_as_uint(zv);
        float z[16];
#pragma unroll
        for (int oo = 0; oo < 16; oo++)
            z[oo] = __uint_as_float(__builtin_amdgcn_readlane(zb, oo * 4));

        float hv_out[2];
#pragma unroll
        for (int h2 = 0; h2 < 2; h2++) {
            float gp_f = bo[0][h2] + z[0]*wo[0][0][h2] + z[1]*wo[0][1][h2] + z[2]*wo[0][2][h2] + z[3]*wo[0][3][h2];
            float gp_i = bo[1][h2] + z[4]*wo[1][0][h2] + z[5]*wo[1][1][h2] + z[6]*wo[1][2][h2] + z[7]*wo[1][3][h2];
            float gp_g = bo[2][h2] + z[8]*wo[2][0][h2] + z[9]*wo[2][1][h2] + z[10]*wo[2][2][h2] + z[11]*wo[2][3][h2];
            float gp_o = bo[3][h2] + z[12]*wo[3][0][h2] + z[13]*wo[3][1][h2] + z[14]*wo[3][2][h2] + z[15]*wo[3][3][h2];
            float fg = sigf(gp_f);
            float ig = sigf(gp_i);
            float gg = tanhf_fast(gp_g);
            float og = sigf(gp_o);
            c[h2] = fg * c[h2] + ig * gg;
            hv_out[h2] = og * tanhf_fast(c[h2]);
        }

        h_lds[lane] = hv_out[0];
        h_lds[lane + 64] = hv_out[1];

        long outbase = (long)t * (B_DIM * H_DIM) + (long)b * H_DIM;
        HS[outbase + lane] = hv_out[0];
        HS[outbase + lane + 64] = hv_out[1];
    }
}

// ---------------------------------------------------------------------------
// Kernel 5: tag head + log_softmax. Block 256 = 8 rows x 32 tags.
// ---------------------------------------------------------------------------
__global__ __launch_bounds__(256) void head_kernel(
    const float* __restrict__ HS, const float* __restrict__ Wtag,
    const float* __restrict__ btag, float* __restrict__ OUT)
{
    __shared__ float wt[128 * 32];
    const int tid = threadIdx.x;
    {
        float4* wt4 = (float4*)wt;
        const float4* wg = (const float4*)Wtag;
#pragma unroll
        for (int i = 0; i < 4; i++) wt4[tid + i * 256] = wg[tid + i * 256];
    }
    __syncthreads();

    long row = (long)blockIdx.x * 8 + (tid >> 5);
    int tag = tid & 31;
    const float4* xr = (const float4*)(HS + row * 128);
    float acc = btag[tag];
#pragma unroll 8
    for (int k4 = 0; k4 < 32; k4++) {
        float4 xv = xr[k4];
        acc += xv.x * wt[(k4 * 4 + 0) * 32 + tag] + xv.y * wt[(k4 * 4 + 1) * 32 + tag]
             + xv.z * wt[(k4 * 4 + 2) * 32 + tag] + xv.w * wt[(k4 * 4 + 3) * 32 + tag];
    }
    float m = acc;
#pragma unroll
    for (int d = 16; d >= 1; d >>= 1) m = fmaxf(m, __shfl_xor(m, d));
    float e = __expf(acc - m);
#pragma unroll
    for (int d = 16; d >= 1; d >>= 1) e += __shfl_xor(e, d);
    OUT[row * 32 + tag] = acc - m - __logf(e);
}

// ---------------------------------------------------------------------------
extern "C" void kernel_launch(void* const* d_in, const int* in_sizes, int n_in,
                              void* d_out, int out_size, void* d_ws, size_t ws_size,
                              hipStream_t stream)
{
    const float* X    = (const float*)d_in[0];   // [T,B,F]
    const float* adj  = (const float*)d_in[1];   // [B,B]
    const float* W1   = (const float*)d_in[2];   // [F,H1]
    const float* b1   = (const float*)d_in[3];
    const float* W2   = (const float*)d_in[4];   // [H1,H]
    const float* b2   = (const float*)d_in[5];
    const float* Win  = (const float*)d_in[6];   // [4,F+H,Q]
    const float* b_in = (const float*)d_in[7];   // [4,Q]
    const float* Wout = (const float*)d_in[8];   // [4,Q,H]
    const float* bout = (const float*)d_in[9];   // [4,H]
    const float* Wtag = (const float*)d_in[10];  // [H,TAGS]
    const float* btag = (const float*)d_in[11];
    float* OUT = (float*)d_out;

    float* ws = (float*)d_ws;
    float* NSP  = ws;                    // [T,B,16]  1,048,576 f
    float* adjT = ws + 1048576;          // [B,B]        65,536 f
    float* AX   = ws + 1114112;          // [T,B,16]  1,048,576 f
    float* HS   = ws + 2162688;          // [T,B,H]   8,388,608 f

    mlp_kernel<<<dim3(TB / 32), dim3(256), 0, stream>>>(X, W1, b1, W2, b2, Win, NSP);
    transpose_kernel<<<dim3(64), dim3(256), 0, stream>>>(adj, adjT);
    aggx_kernel<<<dim3(256), dim3(256), 0, stream>>>(adjT, NSP, b_in, AX);
    lstm_kernel<<<dim3(B_DIM), dim3(64), 0, stream>>>(AX, Win, Wout, bout, HS);
    head_kernel<<<dim3(TB / 8), dim3(256), 0, stream>>>(HS, Wtag, btag, OUT);
}

// Round 6
// 320.498 us; speedup vs baseline: 1.5906x; 1.1392x over previous
//
#include <hip/hip_runtime.h>
#include <hip/hip_bf16.h>

// Problem dims (fixed)
#define T_DIM 256
#define B_DIM 256
#define F_DIM 128
#define H1_DIM 256
#define H_DIM 128
#define Q_DIM 4
#define TAGS 32
#define TB (T_DIM * B_DIM)   // 65536 rows

__device__ __forceinline__ float rcpf(float x) { return __builtin_amdgcn_rcpf(x); }

__device__ __forceinline__ float tanhf_fast(float x) {
    // 1 - 2/(exp(2x)+1): safe at +/-inf. rcp is 1-ulp approx (plenty for 7e-2 abs tol)
    float e = __expf(2.0f * x);
    return 1.0f - 2.0f * rcpf(e + 1.0f);
}
__device__ __forceinline__ float sigf(float x) {
    return rcpf(1.0f + __expf(-x));
}

// DPP cross-lane add within quad: CTRL=0xB1 -> lane^1, CTRL=0x4E -> lane^2
template<int CTRL>
__device__ __forceinline__ float dpp_xadd(float x) {
    int t = __builtin_amdgcn_update_dpp(0, __float_as_int(x), CTRL, 0xF, 0xF, true);
    return x + __int_as_float(t);
}

// ---------------------------------------------------------------------------
// Kernel 1: per-node MLP + fused Win_x projection.
// NSP[row, o] = tanh(tanh(X@W1+b1)@W2+b2) @ Win_x[:,o]     (o = g*4+q, 16 outs)
// Block: 256 threads, 32 rows per block. Grid: TB/32 = 2048.
// ---------------------------------------------------------------------------
__global__ __launch_bounds__(256) void mlp_kernel(
    const float* __restrict__ X, const float* __restrict__ W1,
    const float* __restrict__ b1, const float* __restrict__ W2,
    const float* __restrict__ b2, const float* __restrict__ Win,
    float* __restrict__ NSP)
{
    __shared__ float smemA[32 * 132];   // xs [32][128] then nss [32][132]
    __shared__ float smemB[32 * 256];   // a1s [32][256] then wxsT [16][132]
    const int tid = threadIdx.x;
    const long rowbase = (long)blockIdx.x * 32;

    // stage X tile (32 x 128) into smemA (stride 128)
    {
        const float4* Xg = (const float4*)(X + rowbase * 128);
        float4* xs4 = (float4*)smemA;
#pragma unroll
        for (int i = 0; i < 4; i++) xs4[tid + i * 256] = Xg[tid + i * 256];
    }
    __syncthreads();

    // Phase A: a1 = tanh(x @ W1 + b1)   [32 x 256] -> smemB
    // thread (rg, c0): rows rg*8..+7, cols 4*c0..4*c0+3
    {
        const int rg = tid >> 6;
        const int c0 = tid & 63;
        float4 acc[8];
#pragma unroll
        for (int r = 0; r < 8; r++) acc[r] = make_float4(0.f, 0.f, 0.f, 0.f);

        const float4* xs4 = (const float4*)smemA;
        for (int k4 = 0; k4 < 32; k4++) {
            float4 xv[8];
#pragma unroll
            for (int r = 0; r < 8; r++) xv[r] = xs4[(rg * 8 + r) * 32 + k4];
            float4 wv[4];
#pragma unroll
            for (int kk = 0; kk < 4; kk++)
                wv[kk] = *(const float4*)(W1 + (k4 * 4 + kk) * 256 + c0 * 4);
#pragma unroll
            for (int r = 0; r < 8; r++) {
                acc[r].x += xv[r].x*wv[0].x + xv[r].y*wv[1].x + xv[r].z*wv[2].x + xv[r].w*wv[3].x;
                acc[r].y += xv[r].x*wv[0].y + xv[r].y*wv[1].y + xv[r].z*wv[2].y + xv[r].w*wv[3].y;
                acc[r].z += xv[r].x*wv[0].z + xv[r].y*wv[1].z + xv[r].z*wv[2].z + xv[r].w*wv[3].z;
                acc[r].w += xv[r].x*wv[0].w + xv[r].y*wv[1].w + xv[r].z*wv[2].w + xv[r].w*wv[3].w;
            }
        }
        float4 bv = *(const float4*)(b1 + c0 * 4);
#pragma unroll
        for (int r = 0; r < 8; r++) {
            float4 out;
            out.x = tanhf_fast(acc[r].x + bv.x);
            out.y = tanhf_fast(acc[r].y + bv.y);
            out.z = tanhf_fast(acc[r].z + bv.z);
            out.w = tanhf_fast(acc[r].w + bv.w);
            *(float4*)(&smemB[(rg * 8 + r) * 256 + c0 * 4]) = out;
        }
    }
    __syncthreads();

    // Phase B: ns = tanh(a1 @ W2 + b2)   [32 x 128] -> nss in smemA (stride 132)
    // thread (rg, c0): rows rg*8..+7, cols 2*c0, 2*c0+1
    {
        const int rg = tid >> 6;
        const int c0 = tid & 63;
        float2 acc[8];
#pragma unroll
        for (int r = 0; r < 8; r++) acc[r] = make_float2(0.f, 0.f);

        const float4* a1s4 = (const float4*)smemB;
        for (int k4 = 0; k4 < 64; k4++) {
            float4 av[8];
#pragma unroll
            for (int r = 0; r < 8; r++) av[r] = a1s4[(rg * 8 + r) * 64 + k4];
            float2 wv[4];
#pragma unroll
            for (int kk = 0; kk < 4; kk++)
                wv[kk] = *(const float2*)(W2 + (k4 * 4 + kk) * 128 + c0 * 2);
#pragma unroll
            for (int r = 0; r < 8; r++) {
                acc[r].x += av[r].x*wv[0].x + av[r].y*wv[1].x + av[r].z*wv[2].x + av[r].w*wv[3].x;
                acc[r].y += av[r].x*wv[0].y + av[r].y*wv[1].y + av[r].z*wv[2].y + av[r].w*wv[3].y;
            }
        }
        float2 bv = *(const float2*)(b2 + c0 * 2);
#pragma unroll
        for (int r = 0; r < 8; r++) {
            float2 out;
            out.x = tanhf_fast(acc[r].x + bv.x);
            out.y = tanhf_fast(acc[r].y + bv.y);
            *(float2*)(&smemA[(rg * 8 + r) * 132 + c0 * 2]) = out;
        }
    }
    __syncthreads();   // all Phase-B a1s reads done -> can overwrite smemB

    // stage Win_x transposed: wxsT[o][f] = Win[g][f][q], o=g*4+q  (16 x 132)
    for (int idx = tid; idx < 2048; idx += 256) {
        int o = idx >> 7, f = idx & 127;
        smemB[o * 132 + f] = Win[(o >> 2) * 1024 + f * 4 + (o & 3)];
    }
    __syncthreads();

    // NSP gemm: 32 rows x 16 o, 2 o per thread
    {
        const int row = tid >> 3;
        const int o0 = (tid & 7) * 2;
        const float4* nss4 = (const float4*)smemA;
        const float4* wx4 = (const float4*)smemB;
        float a0 = 0.f, a1 = 0.f;
#pragma unroll
        for (int f4 = 0; f4 < 32; f4++) {
            float4 nv = nss4[row * 33 + f4];
            float4 w0 = wx4[o0 * 33 + f4];
            float4 w1 = wx4[(o0 + 1) * 33 + f4];
            a0 += nv.x * w0.x + nv.y * w0.y + nv.z * w0.z + nv.w * w0.w;
            a1 += nv.x * w1.x + nv.y * w1.y + nv.z * w1.z + nv.w * w1.w;
        }
        long base = (rowbase + row) * 16 + o0;
        NSP[base] = a0;
        NSP[base + 1] = a1;
    }
}

// ---------------------------------------------------------------------------
// Kernel 2: adj transpose (one-time, 256KB). adjT[j][i] = adj[i][j]
// ---------------------------------------------------------------------------
__global__ __launch_bounds__(256) void transpose_kernel(
    const float* __restrict__ adj, float* __restrict__ adjT)
{
    __shared__ float tile[32][33];
    const int tid = threadIdx.x;
    const int bx = blockIdx.x & 7, by = blockIdx.x >> 3;
    const int lx = tid & 31, ly = (tid >> 5) * 4;
#pragma unroll
    for (int r = 0; r < 4; r++)
        tile[ly + r][lx] = adj[(long)(by * 32 + ly + r) * 256 + bx * 32 + lx];
    __syncthreads();
#pragma unroll
    for (int r = 0; r < 4; r++)
        adjT[(long)(bx * 32 + ly + r) * 256 + by * 32 + lx] = tile[lx][ly + r];
}

// ---------------------------------------------------------------------------
// Kernel 3: AX[t,i,o] = b_in[o] + sum_j adj[i,j] * NSP[t,j,o]
// Grid 256 (t), block 256 (i = tid). NSP tile staged in LDS (broadcast reads).
// ---------------------------------------------------------------------------
__global__ __launch_bounds__(256) void aggx_kernel(
    const float* __restrict__ adjT, const float* __restrict__ NSP,
    const float* __restrict__ b_in, float* __restrict__ AX)
{
    __shared__ float4 nsp_s[256 * 4];
    const int tid = threadIdx.x;
    const int t = blockIdx.x;
    {
        const float4* g = (const float4*)(NSP + (long)t * 4096);
#pragma unroll
        for (int i = 0; i < 4; i++) nsp_s[tid + i * 256] = g[tid + i * 256];
    }
    __syncthreads();

    float4 acc[4];
#pragma unroll
    for (int p = 0; p < 4; p++) acc[p] = ((const float4*)b_in)[p];

    const float* arow = adjT + tid;
    float a[8], an[8];
#pragma unroll
    for (int m = 0; m < 8; m++) an[m] = arow[m * 256];
    for (int j0 = 0; j0 < 256; j0 += 8) {
#pragma unroll
        for (int m = 0; m < 8; m++) a[m] = an[m];
        if (j0 + 8 < 256) {
#pragma unroll
            for (int m = 0; m < 8; m++) an[m] = arow[(j0 + 8 + m) * 256];
        }
#pragma unroll
        for (int m = 0; m < 8; m++) {
            float av = a[m];
#pragma unroll
            for (int p = 0; p < 4; p++) {
                float4 nv = nsp_s[(j0 + m) * 4 + p];
                acc[p].x += av * nv.x; acc[p].y += av * nv.y;
                acc[p].z += av * nv.z; acc[p].w += av * nv.w;
            }
        }
    }
    float4* out = (float4*)(AX + (long)t * 4096 + tid * 16);
#pragma unroll
    for (int p = 0; p < 4; p++) out[p] = acc[p];
}

// ---------------------------------------------------------------------------
// Kernel 4: LSTM scan. One wave per batch element, NO barriers, no spills.
// Round-5 fix: NO global stores inside the serial loop (they forced vmcnt
// WAR waits on the store-data registers every step). Full h history lives
// in a 128 KB LDS buffer; HS is written once in a coalesced epilogue.
// Slot (t-1)&255 read trick: slot 255 pre-zeroed, only read at t=0.
// ---------------------------------------------------------------------------
__global__ __attribute__((amdgpu_waves_per_eu(1, 1))) __launch_bounds__(64)
void lstm_kernel(
    const float* __restrict__ AX, const float* __restrict__ Win,
    const float* __restrict__ Wout, const float* __restrict__ b_out,
    float* __restrict__ HS)
{
    __shared__ __align__(16) float hh[T_DIM * 128];   // 128 KB: h after step t

    const int lane = threadIdx.x;
    const int b = blockIdx.x;
    const int o = lane >> 2;
    const int s = lane & 3;
    const int g_o = o >> 2, q_o = o & 3;

    // wh[m*4+j] = Win_h[k][o] with k = m*16 + s*4 + j  (conflict-free h4 reads)
    float wh[32];
#pragma unroll
    for (int m = 0; m < 8; m++)
#pragma unroll
        for (int j = 0; j < 4; j++)
            wh[m * 4 + j] = Win[g_o * 1024 + 512 + (m * 16 + s * 4 + j) * 4 + q_o];

    float wo[4][4][2];
    float bo[4][2];
#pragma unroll
    for (int g = 0; g < 4; g++) {
#pragma unroll
        for (int h2 = 0; h2 < 2; h2++) bo[g][h2] = b_out[g * 128 + lane + 64 * h2];
#pragma unroll
        for (int q = 0; q < 4; q++)
#pragma unroll
            for (int h2 = 0; h2 < 2; h2++)
                wo[g][q][h2] = Wout[(g * 4 + q) * 128 + lane + 64 * h2];
    }

    float c[2] = {0.f, 0.f};
    // pre-zero slot 255 (read as "h before step 0" at t=0, overwritten at t=255
    // only after its last read)
    hh[255 * 128 + lane] = 0.f;
    hh[255 * 128 + 64 + lane] = 0.f;

    // distance-2 AX prefetch pipeline
    float ax_cur = AX[(long)b * 16 + o];
    float ax_nxt = AX[(long)(B_DIM * 16) + (long)b * 16 + o];

    for (int t = 0; t < T_DIM; t++) {
        const float4* hprev = (const float4*)(hh + ((t + 255) & 255) * 128);
        // zpre partial over k = {m*16 + s*4 + j}: 4 chains, 2 half-batches
        float a0 = 0.f, a1 = 0.f, a2 = 0.f, a3 = 0.f;
#pragma unroll
        for (int half = 0; half < 2; half++) {
            float4 hv[4];
#pragma unroll
            for (int m = 0; m < 4; m++) hv[m] = hprev[(half * 4 + m) * 4 + s];
            const float* w = wh + half * 16;
            a0 += hv[0].x*w[0]  + hv[0].y*w[1]  + hv[0].z*w[2]  + hv[0].w*w[3];
            a1 += hv[1].x*w[4]  + hv[1].y*w[5]  + hv[1].z*w[6]  + hv[1].w*w[7];
            a2 += hv[2].x*w[8]  + hv[2].y*w[9]  + hv[2].z*w[10] + hv[2].w*w[11];
            a3 += hv[3].x*w[12] + hv[3].y*w[13] + hv[3].z*w[14] + hv[3].w*w[15];
        }
        float acc = (a0 + a1) + (a2 + a3);
        acc = dpp_xadd<0xB1>(acc);   // + lane^1
        acc = dpp_xadd<0x4E>(acc);   // + lane^2
        float zv = tanhf_fast(acc + ax_cur);

        // rotate distance-2 prefetch
        {
            int tp = t + 2;
            if (tp > T_DIM - 1) tp = T_DIM - 1;
            ax_cur = ax_nxt;
            ax_nxt = AX[(long)tp * (B_DIM * 16) + (long)b * 16 + o];
        }

        // broadcast all 16 z values via readlane (z[oo] lives in quad oo)
        unsigned zb = __float_as_uint(zv);
        float z[16];
#pragma unroll
        for (int oo = 0; oo < 16; oo++)
            z[oo] = __uint_as_float(__builtin_amdgcn_readlane(zb, oo * 4));

        float hv_out[2];
#pragma unroll
        for (int h2 = 0; h2 < 2; h2++) {
            float gp_f = bo[0][h2] + z[0]*wo[0][0][h2] + z[1]*wo[0][1][h2] + z[2]*wo[0][2][h2] + z[3]*wo[0][3][h2];
            float gp_i = bo[1][h2] + z[4]*wo[1][0][h2] + z[5]*wo[1][1][h2] + z[6]*wo[1][2][h2] + z[7]*wo[1][3][h2];
            float gp_g = bo[2][h2] + z[8]*wo[2][0][h2] + z[9]*wo[2][1][h2] + z[10]*wo[2][2][h2] + z[11]*wo[2][3][h2];
            float gp_o = bo[3][h2] + z[12]*wo[3][0][h2] + z[13]*wo[3][1][h2] + z[14]*wo[3][2][h2] + z[15]*wo[3][3][h2];
            float fg = sigf(gp_f);
            float ig = sigf(gp_i);
            float gg = tanhf_fast(gp_g);
            float og = sigf(gp_o);
            c[h2] = fg * c[h2] + ig * gg;
            hv_out[h2] = og * tanhf_fast(c[h2]);
        }

        hh[t * 128 + lane] = hv_out[0];
        hh[t * 128 + 64 + lane] = hv_out[1];
        // no global store in the loop: DS is in-order per wave, next iter's
        // reads are safely ordered after these writes
    }

    // epilogue: bulk copy h history LDS -> HS (coalesced, 2 rows per iter)
    const int half = lane >> 5;          // 0/1 -> row tt / tt+1
    const int col4 = (lane & 31) * 4;    // float4 column
    for (int tt = 0; tt < T_DIM; tt += 2) {
        int trow = tt + half;
        float4 v = *(const float4*)(hh + trow * 128 + col4);
        *(float4*)(HS + ((long)trow * B_DIM + b) * 128 + col4) = v;
    }
}

// ---------------------------------------------------------------------------
// Kernel 5: tag head + log_softmax. Block 256 = 8 rows x 32 tags.
// ---------------------------------------------------------------------------
__global__ __launch_bounds__(256) void head_kernel(
    const float* __restrict__ HS, const float* __restrict__ Wtag,
    const float* __restrict__ btag, float* __restrict__ OUT)
{
    __shared__ float wt[128 * 32];
    const int tid = threadIdx.x;
    {
        float4* wt4 = (float4*)wt;
        const float4* wg = (const float4*)Wtag;
#pragma unroll
        for (int i = 0; i < 4; i++) wt4[tid + i * 256] = wg[tid + i * 256];
    }
    __syncthreads();

    long row = (long)blockIdx.x * 8 + (tid >> 5);
    int tag = tid & 31;
    const float4* xr = (const float4*)(HS + row * 128);
    float acc = btag[tag];
#pragma unroll 8
    for (int k4 = 0; k4 < 32; k4++) {
        float4 xv = xr[k4];
        acc += xv.x * wt[(k4 * 4 + 0) * 32 + tag] + xv.y * wt[(k4 * 4 + 1) * 32 + tag]
             + xv.z * wt[(k4 * 4 + 2) * 32 + tag] + xv.w * wt[(k4 * 4 + 3) * 32 + tag];
    }
    float m = acc;
#pragma unroll
    for (int d = 16; d >= 1; d >>= 1) m = fmaxf(m, __shfl_xor(m, d));
    float e = __expf(acc - m);
#pragma unroll
    for (int d = 16; d >= 1; d >>= 1) e += __shfl_xor(e, d);
    OUT[row * 32 + tag] = acc - m - __logf(e);
}

// ---------------------------------------------------------------------------
extern "C" void kernel_launch(void* const* d_in, const int* in_sizes, int n_in,
                              void* d_out, int out_size, void* d_ws, size_t ws_size,
                              hipStream_t stream)
{
    const float* X    = (const float*)d_in[0];   // [T,B,F]
    const float* adj  = (const float*)d_in[1];   // [B,B]
    const float* W1   = (const float*)d_in[2];   // [F,H1]
    const float* b1   = (const float*)d_in[3];
    const float* W2   = (const float*)d_in[4];   // [H1,H]
    const float* b2   = (const float*)d_in[5];
    const float* Win  = (const float*)d_in[6];   // [4,F+H,Q]
    const float* b_in = (const float*)d_in[7];   // [4,Q]
    const float* Wout = (const float*)d_in[8];   // [4,Q,H]
    const float* bout = (const float*)d_in[9];   // [4,H]
    const float* Wtag = (const float*)d_in[10];  // [H,TAGS]
    const float* btag = (const float*)d_in[11];
    float* OUT = (float*)d_out;

    float* ws = (float*)d_ws;
    float* NSP  = ws;                    // [T,B,16]  1,048,576 f
    float* adjT = ws + 1048576;          // [B,B]        65,536 f
    float* AX   = ws + 1114112;          // [T,B,16]  1,048,576 f
    float* HS   = ws + 2162688;          // [T,B,H]   8,388,608 f

    mlp_kernel<<<dim3(TB / 32), dim3(256), 0, stream>>>(X, W1, b1, W2, b2, Win, NSP);
    transpose_kernel<<<dim3(64), dim3(256), 0, stream>>>(adj, adjT);
    aggx_kernel<<<dim3(256), dim3(256), 0, stream>>>(adjT, NSP, b_in, AX);
    lstm_kernel<<<dim3(B_DIM), dim3(64), 0, stream>>>(AX, Win, Wout, bout, HS);
    head_kernel<<<dim3(TB / 8), dim3(256), 0, stream>>>(HS, Wtag, btag, OUT);
}

// Round 7
// 214.198 us; speedup vs baseline: 2.3800x; 1.4963x over previous
//
#include <hip/hip_runtime.h>
#include <hip/hip_bf16.h>

// Problem dims (fixed)
#define T_DIM 256
#define B_DIM 256
#define F_DIM 128
#define H1_DIM 256
#define H_DIM 128
#define Q_DIM 4
#define TAGS 32
#define TB (T_DIM * B_DIM)   // 65536 rows

typedef __attribute__((ext_vector_type(8))) short bf16x8;
typedef __attribute__((ext_vector_type(4))) float f32x4;

__device__ __forceinline__ float rcpf(float x) { return __builtin_amdgcn_rcpf(x); }

__device__ __forceinline__ float tanhf_fast(float x) {
    float e = __expf(2.0f * x);
    return 1.0f - 2.0f * rcpf(e + 1.0f);
}
__device__ __forceinline__ float sigf(float x) {
    return rcpf(1.0f + __expf(-x));
}

__device__ __forceinline__ unsigned short f2bf(float f) {
    __hip_bfloat16 h = __float2bfloat16(f);   // RNE
    return *reinterpret_cast<unsigned short*>(&h);
}

// DPP cross-lane add within quad: CTRL=0xB1 -> lane^1, CTRL=0x4E -> lane^2
template<int CTRL>
__device__ __forceinline__ float dpp_xadd(float x) {
    int t = __builtin_amdgcn_update_dpp(0, __float_as_int(x), CTRL, 0xF, 0xF, true);
    return x + __int_as_float(t);
}

// ---------------------------------------------------------------------------
// Kernel 0: weight prep. Convert W1, W2, Win_x to bf16 in MFMA B-fragment
// order: Wp[((kk*NB + nb)*64 + lane)*8 + e] = W[kk*32 + (lane>>4)*8 + e]
//                                              [nb*16 + (lane&15)]
// ---------------------------------------------------------------------------
__global__ __launch_bounds__(256) void prep_kernel(
    const float* __restrict__ W1, const float* __restrict__ W2,
    const float* __restrict__ Win, unsigned short* __restrict__ W1p,
    unsigned short* __restrict__ W2p, unsigned short* __restrict__ Winxp)
{
    const int gid0 = blockIdx.x * 256 + threadIdx.x;
    const int gstride = gridDim.x * 256;
    // W1p: 32768 entries (K=128 -> kk 0..3, N=256 -> nb 0..15)
    for (int idx = gid0; idx < 32768; idx += gstride) {
        int e = idx & 7, l = (idx >> 3) & 63, t2 = idx >> 9;
        int nb = t2 & 15, kk = t2 >> 4;
        int k = kk * 32 + (l >> 4) * 8 + e, n = nb * 16 + (l & 15);
        W1p[idx] = f2bf(W1[k * 256 + n]);
    }
    // W2p: 32768 entries (K=256 -> kk 0..7, N=128 -> nb 0..7)
    for (int idx = gid0; idx < 32768; idx += gstride) {
        int e = idx & 7, l = (idx >> 3) & 63, t2 = idx >> 9;
        int nb = t2 & 7, kk = t2 >> 3;
        int k = kk * 32 + (l >> 4) * 8 + e, n = nb * 16 + (l & 15);
        W2p[idx] = f2bf(W2[k * 128 + n]);
    }
    // Winxp: 2048 entries (K=128 -> kk 0..3, N=16 -> nb=0). Winx[k][o]=Win[g][k][q]
    for (int idx = gid0; idx < 2048; idx += gstride) {
        int e = idx & 7, l = (idx >> 3) & 63, kk = idx >> 9;
        int k = kk * 32 + (l >> 4) * 8 + e, o = l & 15;
        Winxp[idx] = f2bf(Win[(o >> 2) * 1024 + k * 4 + (o & 3)]);
    }
}

// ---------------------------------------------------------------------------
// Kernel 1: MFMA MLP + fused Win_x projection.
// NSP[row,o] = tanh(tanh(X@W1+b1)@W2+b2) @ Winx[:,o]
// Block: 256 threads = 4 waves, 64 rows. Grid: TB/64 = 1024.
// mfma_f32_16x16x32_bf16; f32 accumulate; tanh in f32.
// LDS tiles XOR-swizzled (byte ^= (row&7)<<4) for conflict-free ds_read_b128.
// ---------------------------------------------------------------------------
__global__ __launch_bounds__(256) void mlp_mfma_kernel(
    const float* __restrict__ X, const unsigned short* __restrict__ W1p,
    const float* __restrict__ b1, const unsigned short* __restrict__ W2p,
    const float* __restrict__ b2, const unsigned short* __restrict__ Winxp,
    float* __restrict__ NSP)
{
    __shared__ __align__(16) unsigned short a1_s[64 * 256];   // 32 KB, stride 512 B
    __shared__ __align__(16) unsigned short xns_s[64 * 128];  // 16 KB: X, then ns

    const int tid = threadIdx.x;
    const int w = tid >> 6;        // wave 0..3
    const int lane = tid & 63;
    const int lr = lane & 15;      // C col / A row within frag
    const int lg = lane >> 4;      // k-chunk group
    const long rowbase = (long)blockIdx.x * 64;

    char* const a1c = (char*)a1_s;
    char* const xnc = (char*)xns_s;

    // ---- stage X tile (64x128 f32 -> bf16, swizzled) ----
    {
        const int r = tid >> 2;          // row 0..63
        const int qc = tid & 3;          // 32-col quarter
        const float4* xg = (const float4*)(X + (rowbase + r) * 128 + qc * 32);
#pragma unroll
        for (int i = 0; i < 4; i++) {
            float4 lo = xg[i * 2], hi = xg[i * 2 + 1];
            bf16x8 v;
            v[0] = (short)f2bf(lo.x); v[1] = (short)f2bf(lo.y);
            v[2] = (short)f2bf(lo.z); v[3] = (short)f2bf(lo.w);
            v[4] = (short)f2bf(hi.x); v[5] = (short)f2bf(hi.y);
            v[6] = (short)f2bf(hi.z); v[7] = (short)f2bf(hi.w);
            int byte = (r * 256 + qc * 64 + i * 16) ^ ((r & 7) << 4);
            *(bf16x8*)(xnc + byte) = v;
        }
    }
    __syncthreads();

    // ---- Phase A: a1 = tanh(X @ W1 + b1), wave w -> cols w*64..w*64+63 ----
    {
        f32x4 acc[4][4];
#pragma unroll
        for (int mi = 0; mi < 4; mi++)
#pragma unroll
            for (int j = 0; j < 4; j++) acc[mi][j] = (f32x4){0.f, 0.f, 0.f, 0.f};

        const bf16x8* w1v = (const bf16x8*)W1p;
#pragma unroll
        for (int kk = 0; kk < 4; kk++) {
            bf16x8 af[4];
#pragma unroll
            for (int mi = 0; mi < 4; mi++) {
                int row = mi * 16 + lr;
                int byte = (row * 256 + kk * 64 + lg * 16) ^ ((row & 7) << 4);
                af[mi] = *(const bf16x8*)(xnc + byte);
            }
            bf16x8 bf[4];
#pragma unroll
            for (int j = 0; j < 4; j++)
                bf[j] = w1v[(kk * 16 + (w * 4 + j)) * 64 + lane];
#pragma unroll
            for (int mi = 0; mi < 4; mi++)
#pragma unroll
                for (int j = 0; j < 4; j++)
                    acc[mi][j] = __builtin_amdgcn_mfma_f32_16x16x32_bf16(
                        af[mi], bf[j], acc[mi][j], 0, 0, 0);
        }

        float b1v[4];
#pragma unroll
        for (int j = 0; j < 4; j++) b1v[j] = b1[(w * 4 + j) * 16 + lr];
#pragma unroll
        for (int mi = 0; mi < 4; mi++)
#pragma unroll
            for (int j = 0; j < 4; j++)
#pragma unroll
                for (int reg = 0; reg < 4; reg++) {
                    int row = mi * 16 + lg * 4 + reg;
                    int col = (w * 4 + j) * 16 + lr;
                    float v = tanhf_fast(acc[mi][j][reg] + b1v[j]);
                    int byte = (row * 512 + col * 2) ^ ((row & 7) << 4);
                    *(unsigned short*)(a1c + byte) = f2bf(v);
                }
    }
    __syncthreads();

    // ---- Phase B: ns = tanh(a1 @ W2 + b2), wave w -> cols w*32..w*32+31 ----
    {
        f32x4 acc[4][2];
#pragma unroll
        for (int mi = 0; mi < 4; mi++)
#pragma unroll
            for (int j = 0; j < 2; j++) acc[mi][j] = (f32x4){0.f, 0.f, 0.f, 0.f};

        const bf16x8* w2v = (const bf16x8*)W2p;
#pragma unroll
        for (int kk = 0; kk < 8; kk++) {
            bf16x8 af[4];
#pragma unroll
            for (int mi = 0; mi < 4; mi++) {
                int row = mi * 16 + lr;
                int byte = (row * 512 + kk * 64 + lg * 16) ^ ((row & 7) << 4);
                af[mi] = *(const bf16x8*)(a1c + byte);
            }
            bf16x8 bf[2];
#pragma unroll
            for (int j = 0; j < 2; j++)
                bf[j] = w2v[(kk * 8 + (w * 2 + j)) * 64 + lane];
#pragma unroll
            for (int mi = 0; mi < 4; mi++)
#pragma unroll
                for (int j = 0; j < 2; j++)
                    acc[mi][j] = __builtin_amdgcn_mfma_f32_16x16x32_bf16(
                        af[mi], bf[j], acc[mi][j], 0, 0, 0);
        }

        float b2v[2];
#pragma unroll
        for (int j = 0; j < 2; j++) b2v[j] = b2[(w * 2 + j) * 16 + lr];
        // X staging reads finished before the A->B barrier; xns_s now holds ns
#pragma unroll
        for (int mi = 0; mi < 4; mi++)
#pragma unroll
            for (int j = 0; j < 2; j++)
#pragma unroll
                for (int reg = 0; reg < 4; reg++) {
                    int row = mi * 16 + lg * 4 + reg;
                    int col = (w * 2 + j) * 16 + lr;
                    float v = tanhf_fast(acc[mi][j][reg] + b2v[j]);
                    int byte = (row * 256 + col * 2) ^ ((row & 7) << 4);
                    *(unsigned short*)(xnc + byte) = f2bf(v);
                }
    }
    __syncthreads();

    // ---- NSP: nsp = ns @ Winx   (wave w handles rows w*16..w*16+15) ----
    {
        f32x4 acc = (f32x4){0.f, 0.f, 0.f, 0.f};
        const bf16x8* wxv = (const bf16x8*)Winxp;
#pragma unroll
        for (int kk = 0; kk < 4; kk++) {
            int row = w * 16 + lr;
            int byte = (row * 256 + kk * 64 + lg * 16) ^ ((row & 7) << 4);
            bf16x8 af = *(const bf16x8*)(xnc + byte);
            bf16x8 bf = wxv[kk * 64 + lane];
            acc = __builtin_amdgcn_mfma_f32_16x16x32_bf16(af, bf, acc, 0, 0, 0);
        }
#pragma unroll
        for (int reg = 0; reg < 4; reg++) {
            int row = w * 16 + lg * 4 + reg;
            NSP[(rowbase + row) * 16 + lr] = acc[reg];
        }
    }
}

// ---------------------------------------------------------------------------
// Kernel 2: adj transpose (one-time, 256KB). adjT[j][i] = adj[i][j]
// ---------------------------------------------------------------------------
__global__ __launch_bounds__(256) void transpose_kernel(
    const float* __restrict__ adj, float* __restrict__ adjT)
{
    __shared__ float tile[32][33];
    const int tid = threadIdx.x;
    const int bx = blockIdx.x & 7, by = blockIdx.x >> 3;
    const int lx = tid & 31, ly = (tid >> 5) * 4;
#pragma unroll
    for (int r = 0; r < 4; r++)
        tile[ly + r][lx] = adj[(long)(by * 32 + ly + r) * 256 + bx * 32 + lx];
    __syncthreads();
#pragma unroll
    for (int r = 0; r < 4; r++)
        adjT[(long)(bx * 32 + ly + r) * 256 + by * 32 + lx] = tile[lx][ly + r];
}

// ---------------------------------------------------------------------------
// Kernel 3: AX[t,i,o] = b_in[o] + sum_j adj[i,j] * NSP[t,j,o]
// ---------------------------------------------------------------------------
__global__ __launch_bounds__(256) void aggx_kernel(
    const float* __restrict__ adjT, const float* __restrict__ NSP,
    const float* __restrict__ b_in, float* __restrict__ AX)
{
    __shared__ float4 nsp_s[256 * 4];
    const int tid = threadIdx.x;
    const int t = blockIdx.x;
    {
        const float4* g = (const float4*)(NSP + (long)t * 4096);
#pragma unroll
        for (int i = 0; i < 4; i++) nsp_s[tid + i * 256] = g[tid + i * 256];
    }
    __syncthreads();

    float4 acc[4];
#pragma unroll
    for (int p = 0; p < 4; p++) acc[p] = ((const float4*)b_in)[p];

    const float* arow = adjT + tid;
    float a[8], an[8];
#pragma unroll
    for (int m = 0; m < 8; m++) an[m] = arow[m * 256];
    for (int j0 = 0; j0 < 256; j0 += 8) {
#pragma unroll
        for (int m = 0; m < 8; m++) a[m] = an[m];
        if (j0 + 8 < 256) {
#pragma unroll
            for (int m = 0; m < 8; m++) an[m] = arow[(j0 + 8 + m) * 256];
        }
#pragma unroll
        for (int m = 0; m < 8; m++) {
            float av = a[m];
#pragma unroll
            for (int p = 0; p < 4; p++) {
                float4 nv = nsp_s[(j0 + m) * 4 + p];
                acc[p].x += av * nv.x; acc[p].y += av * nv.y;
                acc[p].z += av * nv.z; acc[p].w += av * nv.w;
            }
        }
    }
    float4* out = (float4*)(AX + (long)t * 4096 + tid * 16);
#pragma unroll
    for (int p = 0; p < 4; p++) out[p] = acc[p];
}

// ---------------------------------------------------------------------------
// Kernel 4: LSTM scan. One wave per batch element, no barriers, no spills,
// no global stores in the loop (h history in 128 KB LDS, epilogue copy).
// ---------------------------------------------------------------------------
__global__ __attribute__((amdgpu_waves_per_eu(1, 1))) __launch_bounds__(64)
void lstm_kernel(
    const float* __restrict__ AX, const float* __restrict__ Win,
    const float* __restrict__ Wout, const float* __restrict__ b_out,
    float* __restrict__ HS)
{
    __shared__ __align__(16) float hh[T_DIM * 128];   // 128 KB: h after step t

    const int lane = threadIdx.x;
    const int b = blockIdx.x;
    const int o = lane >> 2;
    const int s = lane & 3;
    const int g_o = o >> 2, q_o = o & 3;

    float wh[32];
#pragma unroll
    for (int m = 0; m < 8; m++)
#pragma unroll
        for (int j = 0; j < 4; j++)
            wh[m * 4 + j] = Win[g_o * 1024 + 512 + (m * 16 + s * 4 + j) * 4 + q_o];

    float wo[4][4][2];
    float bo[4][2];
#pragma unroll
    for (int g = 0; g < 4; g++) {
#pragma unroll
        for (int h2 = 0; h2 < 2; h2++) bo[g][h2] = b_out[g * 128 + lane + 64 * h2];
#pragma unroll
        for (int q = 0; q < 4; q++)
#pragma unroll
            for (int h2 = 0; h2 < 2; h2++)
                wo[g][q][h2] = Wout[(g * 4 + q) * 128 + lane + 64 * h2];
    }

    float c[2] = {0.f, 0.f};
    hh[255 * 128 + lane] = 0.f;
    hh[255 * 128 + 64 + lane] = 0.f;

    float ax_cur = AX[(long)b * 16 + o];
    float ax_nxt = AX[(long)(B_DIM * 16) + (long)b * 16 + o];

    for (int t = 0; t < T_DIM; t++) {
        const float4* hprev = (const float4*)(hh + ((t + 255) & 255) * 128);
        float a0 = 0.f, a1 = 0.f, a2 = 0.f, a3 = 0.f;
#pragma unroll
        for (int half = 0; half < 2; half++) {
            float4 hv[4];
#pragma unroll
            for (int m = 0; m < 4; m++) hv[m] = hprev[(half * 4 + m) * 4 + s];
            const float* w = wh + half * 16;
            a0 += hv[0].x*w[0]  + hv[0].y*w[1]  + hv[0].z*w[2]  + hv[0].w*w[3];
            a1 += hv[1].x*w[4]  + hv[1].y*w[5]  + hv[1].z*w[6]  + hv[1].w*w[7];
            a2 += hv[2].x*w[8]  + hv[2].y*w[9]  + hv[2].z*w[10] + hv[2].w*w[11];
            a3 += hv[3].x*w[12] + hv[3].y*w[13] + hv[3].z*w[14] + hv[3].w*w[15];
        }
        float acc = (a0 + a1) + (a2 + a3);
        acc = dpp_xadd<0xB1>(acc);
        acc = dpp_xadd<0x4E>(acc);
        float zv = tanhf_fast(acc + ax_cur);

        {
            int tp = t + 2;
            if (tp > T_DIM - 1) tp = T_DIM - 1;
            ax_cur = ax_nxt;
            ax_nxt = AX[(long)tp * (B_DIM * 16) + (long)b * 16 + o];
        }

        unsigned zb = __float_as_uint(zv);
        float z[16];
#pragma unroll
        for (int oo = 0; oo < 16; oo++)
            z[oo] = __uint_as_float(__builtin_amdgcn_readlane(zb, oo * 4));

        float hv_out[2];
#pragma unroll
        for (int h2 = 0; h2 < 2; h2++) {
            float gp_f = bo[0][h2] + z[0]*wo[0][0][h2] + z[1]*wo[0][1][h2] + z[2]*wo[0][2][h2] + z[3]*wo[0][3][h2];
            float gp_i = bo[1][h2] + z[4]*wo[1][0][h2] + z[5]*wo[1][1][h2] + z[6]*wo[1][2][h2] + z[7]*wo[1][3][h2];
            float gp_g = bo[2][h2] + z[8]*wo[2][0][h2] + z[9]*wo[2][1][h2] + z[10]*wo[2][2][h2] + z[11]*wo[2][3][h2];
            float gp_o = bo[3][h2] + z[12]*wo[3][0][h2] + z[13]*wo[3][1][h2] + z[14]*wo[3][2][h2] + z[15]*wo[3][3][h2];
            float fg = sigf(gp_f);
            float ig = sigf(gp_i);
            float gg = tanhf_fast(gp_g);
            float og = sigf(gp_o);
            c[h2] = fg * c[h2] + ig * gg;
            hv_out[h2] = og * tanhf_fast(c[h2]);
        }

        hh[t * 128 + lane] = hv_out[0];
        hh[t * 128 + 64 + lane] = hv_out[1];
    }

    const int half = lane >> 5;
    const int col4 = (lane & 31) * 4;
    for (int tt = 0; tt < T_DIM; tt += 2) {
        int trow = tt + half;
        float4 v = *(const float4*)(hh + trow * 128 + col4);
        *(float4*)(HS + ((long)trow * B_DIM + b) * 128 + col4) = v;
    }
}

// ---------------------------------------------------------------------------
// Kernel 5: tag head + log_softmax. Block 256 = 8 rows x 32 tags.
// ---------------------------------------------------------------------------
__global__ __launch_bounds__(256) void head_kernel(
    const float* __restrict__ HS, const float* __restrict__ Wtag,
    const float* __restrict__ btag, float* __restrict__ OUT)
{
    __shared__ float wt[128 * 32];
    const int tid = threadIdx.x;
    {
        float4* wt4 = (float4*)wt;
        const float4* wg = (const float4*)Wtag;
#pragma unroll
        for (int i = 0; i < 4; i++) wt4[tid + i * 256] = wg[tid + i * 256];
    }
    __syncthreads();

    long row = (long)blockIdx.x * 8 + (tid >> 5);
    int tag = tid & 31;
    const float4* xr = (const float4*)(HS + row * 128);
    float acc = btag[tag];
#pragma unroll 8
    for (int k4 = 0; k4 < 32; k4++) {
        float4 xv = xr[k4];
        acc += xv.x * wt[(k4 * 4 + 0) * 32 + tag] + xv.y * wt[(k4 * 4 + 1) * 32 + tag]
             + xv.z * wt[(k4 * 4 + 2) * 32 + tag] + xv.w * wt[(k4 * 4 + 3) * 32 + tag];
    }
    float m = acc;
#pragma unroll
    for (int d = 16; d >= 1; d >>= 1) m = fmaxf(m, __shfl_xor(m, d));
    float e = __expf(acc - m);
#pragma unroll
    for (int d = 16; d >= 1; d >>= 1) e += __shfl_xor(e, d);
    OUT[row * 32 + tag] = acc - m - __logf(e);
}

// ---------------------------------------------------------------------------
extern "C" void kernel_launch(void* const* d_in, const int* in_sizes, int n_in,
                              void* d_out, int out_size, void* d_ws, size_t ws_size,
                              hipStream_t stream)
{
    const float* X    = (const float*)d_in[0];   // [T,B,F]
    const float* adj  = (const float*)d_in[1];   // [B,B]
    const float* W1   = (const float*)d_in[2];   // [F,H1]
    const float* b1   = (const float*)d_in[3];
    const float* W2   = (const float*)d_in[4];   // [H1,H]
    const float* b2   = (const float*)d_in[5];
    const float* Win  = (const float*)d_in[6];   // [4,F+H,Q]
    const float* b_in = (const float*)d_in[7];   // [4,Q]
    const float* Wout = (const float*)d_in[8];   // [4,Q,H]
    const float* bout = (const float*)d_in[9];   // [4,H]
    const float* Wtag = (const float*)d_in[10];  // [H,TAGS]
    const float* btag = (const float*)d_in[11];
    float* OUT = (float*)d_out;

    float* ws = (float*)d_ws;
    float* NSP  = ws;                    // [T,B,16]  1,048,576 f
    float* adjT = ws + 1048576;          // [B,B]        65,536 f
    float* AX   = ws + 1114112;          // [T,B,16]  1,048,576 f
    float* HS   = ws + 2162688;          // [T,B,H]   8,388,608 f
    unsigned short* W1p   = (unsigned short*)(ws + 10551296);  // 32768 bf16
    unsigned short* W2p   = W1p + 32768;                       // 32768 bf16
    unsigned short* Winxp = W2p + 32768;                       //  2048 bf16

    prep_kernel<<<dim3(64), dim3(256), 0, stream>>>(W1, W2, Win, W1p, W2p, Winxp);
    mlp_mfma_kernel<<<dim3(TB / 64), dim3(256), 0, stream>>>(X, W1p, b1, W2p, b2, Winxp, NSP);
    transpose_kernel<<<dim3(64), dim3(256), 0, stream>>>(adj, adjT);
    aggx_kernel<<<dim3(256), dim3(256), 0, stream>>>(adjT, NSP, b_in, AX);
    lstm_kernel<<<dim3(B_DIM), dim3(64), 0, stream>>>(AX, Win, Wout, bout, HS);
    head_kernel<<<dim3(TB / 8), dim3(256), 0, stream>>>(HS, Wtag, btag, OUT);
}

// Round 8
// 186.014 us; speedup vs baseline: 2.7406x; 1.1515x over previous
//
#include <hip/hip_runtime.h>
#include <hip/hip_bf16.h>

// Problem dims (fixed)
#define T_DIM 256
#define B_DIM 256
#define F_DIM 128
#define H1_DIM 256
#define H_DIM 128
#define Q_DIM 4
#define TAGS 32
#define TB (T_DIM * B_DIM)   // 65536 rows

typedef __attribute__((ext_vector_type(8))) short bf16x8;
typedef __attribute__((ext_vector_type(4))) float f32x4;

__device__ __forceinline__ float rcpf(float x) { return __builtin_amdgcn_rcpf(x); }
__device__ __forceinline__ float exp2f_hw(float x) { return __builtin_amdgcn_exp2f(x); }

// v_exp_f32 IS exp2: fold the 2x / -x scaling into the log2e constant so each
// activation has exactly one mul + one v_exp + one v_rcp in the chain.
__device__ __forceinline__ float tanhf_fast(float x) {
    float e = exp2f_hw(2.885390081777927f * x);   // exp(2x)
    return 1.0f - 2.0f * rcpf(e + 1.0f);
}
__device__ __forceinline__ float sigf(float x) {
    return rcpf(1.0f + exp2f_hw(-1.4426950408889634f * x));
}

__device__ __forceinline__ unsigned short f2bf(float f) {
    __hip_bfloat16 h = __float2bfloat16(f);   // RNE
    return *reinterpret_cast<unsigned short*>(&h);
}

// DPP cross-lane add within quad: CTRL=0xB1 -> lane^1, CTRL=0x4E -> lane^2
template<int CTRL>
__device__ __forceinline__ float dpp_xadd(float x) {
    int t = __builtin_amdgcn_update_dpp(0, __float_as_int(x), CTRL, 0xF, 0xF, true);
    return x + __int_as_float(t);
}

// ---------------------------------------------------------------------------
// Kernel 0: weight prep into MFMA B-fragment order (bf16).
// Wp[((kk*NB + nb)*64 + lane)*8 + e] = W[kk*32 + (lane>>4)*8 + e][nb*16 + (lane&15)]
// ---------------------------------------------------------------------------
__global__ __launch_bounds__(256) void prep_kernel(
    const float* __restrict__ W1, const float* __restrict__ W2,
    const float* __restrict__ Win, const float* __restrict__ Wtag,
    unsigned short* __restrict__ W1p, unsigned short* __restrict__ W2p,
    unsigned short* __restrict__ Winxp, unsigned short* __restrict__ Wtagp)
{
    const int gid0 = blockIdx.x * 256 + threadIdx.x;
    const int gstride = gridDim.x * 256;
    // W1p: K=128 (kk 0..3), N=256 (nb 0..15)
    for (int idx = gid0; idx < 32768; idx += gstride) {
        int e = idx & 7, l = (idx >> 3) & 63, t2 = idx >> 9;
        int nb = t2 & 15, kk = t2 >> 4;
        int k = kk * 32 + (l >> 4) * 8 + e, n = nb * 16 + (l & 15);
        W1p[idx] = f2bf(W1[k * 256 + n]);
    }
    // W2p: K=256 (kk 0..7), N=128 (nb 0..7)
    for (int idx = gid0; idx < 32768; idx += gstride) {
        int e = idx & 7, l = (idx >> 3) & 63, t2 = idx >> 9;
        int nb = t2 & 7, kk = t2 >> 3;
        int k = kk * 32 + (l >> 4) * 8 + e, n = nb * 16 + (l & 15);
        W2p[idx] = f2bf(W2[k * 128 + n]);
    }
    // Winxp: K=128 (kk 0..3), N=16. Winx[k][o] = Win[g][k][q], o=g*4+q
    for (int idx = gid0; idx < 2048; idx += gstride) {
        int e = idx & 7, l = (idx >> 3) & 63, kk = idx >> 9;
        int k = kk * 32 + (l >> 4) * 8 + e, o = l & 15;
        Winxp[idx] = f2bf(Win[(o >> 2) * 1024 + k * 4 + (o & 3)]);
    }
    // Wtagp: K=128 (kk 0..3), N=32 (nt 0..1)
    for (int idx = gid0; idx < 4096; idx += gstride) {
        int e = idx & 7, l = (idx >> 3) & 63, t2 = idx >> 9;
        int nt = t2 & 1, kk = t2 >> 1;
        int k = kk * 32 + (l >> 4) * 8 + e, n = nt * 16 + (l & 15);
        Wtagp[idx] = f2bf(Wtag[k * 32 + n]);
    }
}

// ---------------------------------------------------------------------------
// Kernel 1: MFMA MLP + fused Win_x projection.
// NSP[row,o] = tanh(tanh(X@W1+b1)@W2+b2) @ Winx[:,o]
// ---------------------------------------------------------------------------
__global__ __launch_bounds__(256) void mlp_mfma_kernel(
    const float* __restrict__ X, const unsigned short* __restrict__ W1p,
    const float* __restrict__ b1, const unsigned short* __restrict__ W2p,
    const float* __restrict__ b2, const unsigned short* __restrict__ Winxp,
    float* __restrict__ NSP)
{
    __shared__ __align__(16) unsigned short a1_s[64 * 256];   // 32 KB, stride 512 B
    __shared__ __align__(16) unsigned short xns_s[64 * 128];  // 16 KB: X, then ns

    const int tid = threadIdx.x;
    const int w = tid >> 6;
    const int lane = tid & 63;
    const int lr = lane & 15;
    const int lg = lane >> 4;
    const long rowbase = (long)blockIdx.x * 64;

    char* const a1c = (char*)a1_s;
    char* const xnc = (char*)xns_s;

    // ---- stage X tile (64x128 f32 -> bf16, swizzled) ----
    {
        const int r = tid >> 2;
        const int qc = tid & 3;
        const float4* xg = (const float4*)(X + (rowbase + r) * 128 + qc * 32);
#pragma unroll
        for (int i = 0; i < 4; i++) {
            float4 lo = xg[i * 2], hi = xg[i * 2 + 1];
            bf16x8 v;
            v[0] = (short)f2bf(lo.x); v[1] = (short)f2bf(lo.y);
            v[2] = (short)f2bf(lo.z); v[3] = (short)f2bf(lo.w);
            v[4] = (short)f2bf(hi.x); v[5] = (short)f2bf(hi.y);
            v[6] = (short)f2bf(hi.z); v[7] = (short)f2bf(hi.w);
            int byte = (r * 256 + qc * 64 + i * 16) ^ ((r & 7) << 4);
            *(bf16x8*)(xnc + byte) = v;
        }
    }
    __syncthreads();

    // ---- Phase A: a1 = tanh(X @ W1 + b1), wave w -> cols w*64..+63 ----
    {
        f32x4 acc[4][4];
#pragma unroll
        for (int mi = 0; mi < 4; mi++)
#pragma unroll
            for (int j = 0; j < 4; j++) acc[mi][j] = (f32x4){0.f, 0.f, 0.f, 0.f};

        const bf16x8* w1v = (const bf16x8*)W1p;
#pragma unroll
        for (int kk = 0; kk < 4; kk++) {
            bf16x8 af[4];
#pragma unroll
            for (int mi = 0; mi < 4; mi++) {
                int row = mi * 16 + lr;
                int byte = (row * 256 + kk * 64 + lg * 16) ^ ((row & 7) << 4);
                af[mi] = *(const bf16x8*)(xnc + byte);
            }
            bf16x8 bfv[4];
#pragma unroll
            for (int j = 0; j < 4; j++)
                bfv[j] = w1v[(kk * 16 + (w * 4 + j)) * 64 + lane];
#pragma unroll
            for (int mi = 0; mi < 4; mi++)
#pragma unroll
                for (int j = 0; j < 4; j++)
                    acc[mi][j] = __builtin_amdgcn_mfma_f32_16x16x32_bf16(
                        af[mi], bfv[j], acc[mi][j], 0, 0, 0);
        }

        float b1v[4];
#pragma unroll
        for (int j = 0; j < 4; j++) b1v[j] = b1[(w * 4 + j) * 16 + lr];
#pragma unroll
        for (int mi = 0; mi < 4; mi++)
#pragma unroll
            for (int j = 0; j < 4; j++)
#pragma unroll
                for (int reg = 0; reg < 4; reg++) {
                    int row = mi * 16 + lg * 4 + reg;
                    int col = (w * 4 + j) * 16 + lr;
                    float v = tanhf_fast(acc[mi][j][reg] + b1v[j]);
                    int byte = (row * 512 + col * 2) ^ ((row & 7) << 4);
                    *(unsigned short*)(a1c + byte) = f2bf(v);
                }
    }
    __syncthreads();

    // ---- Phase B: ns = tanh(a1 @ W2 + b2), wave w -> cols w*32..+31 ----
    {
        f32x4 acc[4][2];
#pragma unroll
        for (int mi = 0; mi < 4; mi++)
#pragma unroll
            for (int j = 0; j < 2; j++) acc[mi][j] = (f32x4){0.f, 0.f, 0.f, 0.f};

        const bf16x8* w2v = (const bf16x8*)W2p;
#pragma unroll
        for (int kk = 0; kk < 8; kk++) {
            bf16x8 af[4];
#pragma unroll
            for (int mi = 0; mi < 4; mi++) {
                int row = mi * 16 + lr;
                int byte = (row * 512 + kk * 64 + lg * 16) ^ ((row & 7) << 4);
                af[mi] = *(const bf16x8*)(a1c + byte);
            }
            bf16x8 bfv[2];
#pragma unroll
            for (int j = 0; j < 2; j++)
                bfv[j] = w2v[(kk * 8 + (w * 2 + j)) * 64 + lane];
#pragma unroll
            for (int mi = 0; mi < 4; mi++)
#pragma unroll
                for (int j = 0; j < 2; j++)
                    acc[mi][j] = __builtin_amdgcn_mfma_f32_16x16x32_bf16(
                        af[mi], bfv[j], acc[mi][j], 0, 0, 0);
        }

        float b2v[2];
#pragma unroll
        for (int j = 0; j < 2; j++) b2v[j] = b2[(w * 2 + j) * 16 + lr];
#pragma unroll
        for (int mi = 0; mi < 4; mi++)
#pragma unroll
            for (int j = 0; j < 2; j++)
#pragma unroll
                for (int reg = 0; reg < 4; reg++) {
                    int row = mi * 16 + lg * 4 + reg;
                    int col = (w * 2 + j) * 16 + lr;
                    float v = tanhf_fast(acc[mi][j][reg] + b2v[j]);
                    int byte = (row * 256 + col * 2) ^ ((row & 7) << 4);
                    *(unsigned short*)(xnc + byte) = f2bf(v);
                }
    }
    __syncthreads();

    // ---- NSP: nsp = ns @ Winx   (wave w -> rows w*16..+15) ----
    {
        f32x4 acc = (f32x4){0.f, 0.f, 0.f, 0.f};
        const bf16x8* wxv = (const bf16x8*)Winxp;
#pragma unroll
        for (int kk = 0; kk < 4; kk++) {
            int row = w * 16 + lr;
            int byte = (row * 256 + kk * 64 + lg * 16) ^ ((row & 7) << 4);
            bf16x8 af = *(const bf16x8*)(xnc + byte);
            bf16x8 bfv = wxv[kk * 64 + lane];
            acc = __builtin_amdgcn_mfma_f32_16x16x32_bf16(af, bfv, acc, 0, 0, 0);
        }
#pragma unroll
        for (int reg = 0; reg < 4; reg++) {
            int row = w * 16 + lg * 4 + reg;
            NSP[(rowbase + row) * 16 + lr] = acc[reg];
        }
    }
}

// ---------------------------------------------------------------------------
// Kernel 2: adj transpose. adjT[j][i] = adj[i][j]
// ---------------------------------------------------------------------------
__global__ __launch_bounds__(256) void transpose_kernel(
    const float* __restrict__ adj, float* __restrict__ adjT)
{
    __shared__ float tile[32][33];
    const int tid = threadIdx.x;
    const int bx = blockIdx.x & 7, by = blockIdx.x >> 3;
    const int lx = tid & 31, ly = (tid >> 5) * 4;
#pragma unroll
    for (int r = 0; r < 4; r++)
        tile[ly + r][lx] = adj[(long)(by * 32 + ly + r) * 256 + bx * 32 + lx];
    __syncthreads();
#pragma unroll
    for (int r = 0; r < 4; r++)
        adjT[(long)(bx * 32 + ly + r) * 256 + by * 32 + lx] = tile[lx][ly + r];
}

// ---------------------------------------------------------------------------
// Kernel 3: AX[t,i,o] = b_in[o] + sum_j adj[i,j] * NSP[t,j,o]
// ---------------------------------------------------------------------------
__global__ __launch_bounds__(256) void aggx_kernel(
    const float* __restrict__ adjT, const float* __restrict__ NSP,
    const float* __restrict__ b_in, float* __restrict__ AX)
{
    __shared__ float4 nsp_s[256 * 4];
    const int tid = threadIdx.x;
    const int t = blockIdx.x;
    {
        const float4* g = (const float4*)(NSP + (long)t * 4096);
#pragma unroll
        for (int i = 0; i < 4; i++) nsp_s[tid + i * 256] = g[tid + i * 256];
    }
    __syncthreads();

    float4 acc[4];
#pragma unroll
    for (int p = 0; p < 4; p++) acc[p] = ((const float4*)b_in)[p];

    const float* arow = adjT + tid;
    float a[8], an[8];
#pragma unroll
    for (int m = 0; m < 8; m++) an[m] = arow[m * 256];
    for (int j0 = 0; j0 < 256; j0 += 8) {
#pragma unroll
        for (int m = 0; m < 8; m++) a[m] = an[m];
        if (j0 + 8 < 256) {
#pragma unroll
            for (int m = 0; m < 8; m++) an[m] = arow[(j0 + 8 + m) * 256];
        }
#pragma unroll
        for (int m = 0; m < 8; m++) {
            float av = a[m];
#pragma unroll
            for (int p = 0; p < 4; p++) {
                float4 nv = nsp_s[(j0 + m) * 4 + p];
                acc[p].x += av * nv.x; acc[p].y += av * nv.y;
                acc[p].z += av * nv.z; acc[p].w += av * nv.w;
            }
        }
    }
    float4* out = (float4*)(AX + (long)t * 4096 + tid * 16);
#pragma unroll
    for (int p = 0; p < 4; p++) out[p] = acc[p];
}

// ---------------------------------------------------------------------------
// Kernel 4: LSTM scan + FUSED tag head. One wave per batch element.
// h history in 128 KB LDS (XOR-swizzled rows); after the scan, an MFMA
// epilogue computes logits = hh @ Wtag + btag and log_softmax, writing OUT
// directly. No HS buffer, no separate head kernel.
// ---------------------------------------------------------------------------
__device__ __forceinline__ int hhoff(int row, int inrow) {
    return (row * 512 + inrow) ^ ((row & 7) << 4);
}

__global__ __attribute__((amdgpu_waves_per_eu(1, 1))) __launch_bounds__(64)
void lstm_head_kernel(
    const float* __restrict__ AX, const float* __restrict__ Win,
    const float* __restrict__ Wout, const float* __restrict__ b_out,
    const unsigned short* __restrict__ Wtagp, const float* __restrict__ btag,
    float* __restrict__ OUT)
{
    __shared__ __align__(16) float hh[T_DIM * 128];   // 128 KB, swizzled rows
    char* const hhc = (char*)hh;

    const int lane = threadIdx.x;
    const int b = blockIdx.x;
    const int o = lane >> 2;
    const int s = lane & 3;
    const int g_o = o >> 2, q_o = o & 3;

    // wh[m*4+j] = Win_h[k][o], k = m*16 + s*4 + j
    float wh[32];
#pragma unroll
    for (int m = 0; m < 8; m++)
#pragma unroll
        for (int j = 0; j < 4; j++)
            wh[m * 4 + j] = Win[g_o * 1024 + 512 + (m * 16 + s * 4 + j) * 4 + q_o];

    float wo[4][4][2];
    float bo[4][2];
#pragma unroll
    for (int g = 0; g < 4; g++) {
#pragma unroll
        for (int h2 = 0; h2 < 2; h2++) bo[g][h2] = b_out[g * 128 + lane + 64 * h2];
#pragma unroll
        for (int q = 0; q < 4; q++)
#pragma unroll
            for (int h2 = 0; h2 < 2; h2++)
                wo[g][q][h2] = Wout[(g * 4 + q) * 128 + lane + 64 * h2];
    }

    float c[2] = {0.f, 0.f};
    *(float*)(hhc + hhoff(255, lane * 4)) = 0.f;
    *(float*)(hhc + hhoff(255, 256 + lane * 4)) = 0.f;

    // distance-2 AX prefetch, pointer-bump addressing
    const float* axp = AX + (long)b * 16 + o;
    float ax_cur = axp[0];
    float ax_nxt = axp[B_DIM * 16];
    axp += 2 * B_DIM * 16;

    for (int t = 0; t < T_DIM; t++) {
        const int rp = (t + 255) & 255;
        float a0 = 0.f, a1 = 0.f, a2 = 0.f, a3 = 0.f;
#pragma unroll
        for (int half = 0; half < 2; half++) {
            float4 hv[4];
#pragma unroll
            for (int m = 0; m < 4; m++)
                hv[m] = *(const float4*)(hhc + hhoff(rp, (half * 4 + m) * 64 + s * 16));
            const float* w = wh + half * 16;
            a0 += hv[0].x*w[0]  + hv[0].y*w[1]  + hv[0].z*w[2]  + hv[0].w*w[3];
            a1 += hv[1].x*w[4]  + hv[1].y*w[5]  + hv[1].z*w[6]  + hv[1].w*w[7];
            a2 += hv[2].x*w[8]  + hv[2].y*w[9]  + hv[2].z*w[10] + hv[2].w*w[11];
            a3 += hv[3].x*w[12] + hv[3].y*w[13] + hv[3].z*w[14] + hv[3].w*w[15];
        }
        float acc = (a0 + a1) + (a2 + a3);
        acc = dpp_xadd<0xB1>(acc);
        acc = dpp_xadd<0x4E>(acc);
        float zv = tanhf_fast(acc + ax_cur);

        // rotate distance-2 prefetch (clamped pointer bump)
        ax_cur = ax_nxt;
        ax_nxt = *axp;
        if (t < T_DIM - 3) axp += B_DIM * 16;

        unsigned zb = __float_as_uint(zv);
        float z[16];
#pragma unroll
        for (int oo = 0; oo < 16; oo++)
            z[oo] = __uint_as_float(__builtin_amdgcn_readlane(zb, oo * 4));

        float hv_out[2];
#pragma unroll
        for (int h2 = 0; h2 < 2; h2++) {
            float gp_f = bo[0][h2] + z[0]*wo[0][0][h2] + z[1]*wo[0][1][h2] + z[2]*wo[0][2][h2] + z[3]*wo[0][3][h2];
            float gp_i = bo[1][h2] + z[4]*wo[1][0][h2] + z[5]*wo[1][1][h2] + z[6]*wo[1][2][h2] + z[7]*wo[1][3][h2];
            float gp_g = bo[2][h2] + z[8]*wo[2][0][h2] + z[9]*wo[2][1][h2] + z[10]*wo[2][2][h2] + z[11]*wo[2][3][h2];
            float gp_o = bo[3][h2] + z[12]*wo[3][0][h2] + z[13]*wo[3][1][h2] + z[14]*wo[3][2][h2] + z[15]*wo[3][3][h2];
            float fg = sigf(gp_f);
            float ig = sigf(gp_i);
            float gg = tanhf_fast(gp_g);
            float og = sigf(gp_o);
            c[h2] = fg * c[h2] + ig * gg;
            hv_out[h2] = og * tanhf_fast(c[h2]);
        }

        *(float*)(hhc + hhoff(t, lane * 4)) = hv_out[0];
        *(float*)(hhc + hhoff(t, 256 + lane * 4)) = hv_out[1];
    }

    // ================= fused tag head =================
    // logits[256t x 32tag] = hh @ Wtag + btag ; out = log_softmax(rows)
    const int lr = lane & 15;
    const int lg = lane >> 4;
    const bf16x8* wtv = (const bf16x8*)Wtagp;
    bf16x8 wt[4][2];
#pragma unroll
    for (int kk = 0; kk < 4; kk++)
#pragma unroll
        for (int nt = 0; nt < 2; nt++)
            wt[kk][nt] = wtv[(kk * 2 + nt) * 64 + lane];
    float bt0 = btag[lr], bt1 = btag[16 + lr];

    for (int mi = 0; mi < 16; mi++) {
        f32x4 acc0 = (f32x4){0.f, 0.f, 0.f, 0.f};
        f32x4 acc1 = (f32x4){0.f, 0.f, 0.f, 0.f};
        const int arow = mi * 16 + lr;
#pragma unroll
        for (int kk = 0; kk < 4; kk++) {
            float4 lo = *(const float4*)(hhc + hhoff(arow, kk * 128 + lg * 32));
            float4 hi = *(const float4*)(hhc + hhoff(arow, kk * 128 + lg * 32 + 16));
            bf16x8 af;
            af[0] = (short)f2bf(lo.x); af[1] = (short)f2bf(lo.y);
            af[2] = (short)f2bf(lo.z); af[3] = (short)f2bf(lo.w);
            af[4] = (short)f2bf(hi.x); af[5] = (short)f2bf(hi.y);
            af[6] = (short)f2bf(hi.z); af[7] = (short)f2bf(hi.w);
            acc0 = __builtin_amdgcn_mfma_f32_16x16x32_bf16(af, wt[kk][0], acc0, 0, 0, 0);
            acc1 = __builtin_amdgcn_mfma_f32_16x16x32_bf16(af, wt[kk][1], acc1, 0, 0, 0);
        }
        // per-row (over 32 tags) log_softmax. Row r = mi*16 + lg*4 + reg is
        // held by the 16 lanes of group lg (cols = lane&15).
        float s0[4], s1[4], mx[4], se[4];
#pragma unroll
        for (int reg = 0; reg < 4; reg++) {
            s0[reg] = acc0[reg] + bt0;
            s1[reg] = acc1[reg] + bt1;
            float m = fmaxf(s0[reg], s1[reg]);
#pragma unroll
            for (int d = 8; d >= 1; d >>= 1) m = fmaxf(m, __shfl_xor(m, d));
            mx[reg] = m;
            float e = __expf(s0[reg] - m) + __expf(s1[reg] - m);
#pragma unroll
            for (int d = 8; d >= 1; d >>= 1) e += __shfl_xor(e, d);
            se[reg] = __logf(e);
        }
#pragma unroll
        for (int reg = 0; reg < 4; reg++) {
            long t = mi * 16 + lg * 4 + reg;
            long base = (t * B_DIM + b) * 32;
            OUT[base + lr]      = s0[reg] - mx[reg] - se[reg];
            OUT[base + 16 + lr] = s1[reg] - mx[reg] - se[reg];
        }
    }
}

// ---------------------------------------------------------------------------
extern "C" void kernel_launch(void* const* d_in, const int* in_sizes, int n_in,
                              void* d_out, int out_size, void* d_ws, size_t ws_size,
                              hipStream_t stream)
{
    const float* X    = (const float*)d_in[0];   // [T,B,F]
    const float* adj  = (const float*)d_in[1];   // [B,B]
    const float* W1   = (const float*)d_in[2];   // [F,H1]
    const float* b1   = (const float*)d_in[3];
    const float* W2   = (const float*)d_in[4];   // [H1,H]
    const float* b2   = (const float*)d_in[5];
    const float* Win  = (const float*)d_in[6];   // [4,F+H,Q]
    const float* b_in = (const float*)d_in[7];   // [4,Q]
    const float* Wout = (const float*)d_in[8];   // [4,Q,H]
    const float* bout = (const float*)d_in[9];   // [4,H]
    const float* Wtag = (const float*)d_in[10];  // [H,TAGS]
    const float* btag = (const float*)d_in[11];
    float* OUT = (float*)d_out;

    float* ws = (float*)d_ws;
    float* NSP  = ws;                    // [T,B,16]  1,048,576 f
    float* adjT = ws + 1048576;          // [B,B]        65,536 f
    float* AX   = ws + 1114112;          // [T,B,16]  1,048,576 f
    unsigned short* W1p   = (unsigned short*)(ws + 2162688);   // 32768 bf16
    unsigned short* W2p   = W1p + 32768;                       // 32768 bf16
    unsigned short* Winxp = W2p + 32768;                       //  2048 bf16
    unsigned short* Wtagp = Winxp + 2048;                      //  4096 bf16

    prep_kernel<<<dim3(64), dim3(256), 0, stream>>>(W1, W2, Win, Wtag, W1p, W2p, Winxp, Wtagp);
    mlp_mfma_kernel<<<dim3(TB / 64), dim3(256), 0, stream>>>(X, W1p, b1, W2p, b2, Winxp, NSP);
    transpose_kernel<<<dim3(64), dim3(256), 0, stream>>>(adj, adjT);
    aggx_kernel<<<dim3(256), dim3(256), 0, stream>>>(adjT, NSP, b_in, AX);
    lstm_head_kernel<<<dim3(B_DIM), dim3(64), 0, stream>>>(AX, Win, Wout, bout, Wtagp, btag, OUT);
}